// Round 6
// baseline (2520.173 us; speedup 1.0000x reference)
//
#include <hip/hip_runtime.h>
#include <math.h>

#define B_SZ 64
#define WID 128
#define NPT 4096
#define MODES 128
#define LSEG 20
#define MCH 8
#define LM 160   // LSEG*MCH

typedef _Float16 half8 __attribute__((ext_vector_type(8)));
typedef float f32x4 __attribute__((ext_vector_type(4)));

#define LO_SCALE 2048.0f
#define LO_INV   (1.0f/2048.0f)

// ---------------- workspace layout (bytes), total ~161.3 MB ----------------
static constexpr size_t BY_F    = 0;                       // fp32 [8192][256]
static constexpr size_t BY_wsum = BY_F + 8388608;          // fp32 [4][4][128][128]
static constexpr size_t BY_Wcre = BY_wsum + 1048576;       // fp32 [160][128]
static constexpr size_t BY_Wcim = BY_Wcre + 81920;
static constexpr size_t BY_wl   = BY_Wcim + 81920;         // fp32 [160] (pad)
static constexpr size_t BY_wr   = BY_wl + 1024;
static constexpr size_t BY_li   = BY_wr + 1024;            // int [160]
static constexpr size_t BY_magp = BY_li + 1024;            // fp32 [64][8][128]
static constexpr size_t BY_gate = BY_magp + 262144;        // fp32 [64][128]
static constexpr size_t BY_hh   = BY_gate + 32768;         // f16 [64][128][4096] split-hi
static constexpr size_t BY_hl   = BY_hh + 67108864;        // f16 split-lo
static constexpr size_t BY_Tfh  = BY_hl + 67108864;        // f16 [256][4096]
static constexpr size_t BY_Tfl  = BY_Tfh + 2097152;
static constexpr size_t BY_Tih  = BY_Tfl + 2097152;        // f16 [4096][256]
static constexpr size_t BY_Til  = BY_Tih + 2097152;
static constexpr size_t BY_Xh   = BY_Til + 2097152;        // f16 [64][128][256]
static constexpr size_t BY_Xl   = BY_Xh + 4194304;
static constexpr size_t BY_cWh  = BY_Xl + 4194304;         // f16 [4][128][128]
static constexpr size_t BY_cWl  = BY_cWh + 131072;
static constexpr size_t BY_f1h  = BY_cWl + 131072;         // f16 [128][128]
static constexpr size_t BY_f1l  = BY_f1h + 32768;
static constexpr size_t BY_end  = BY_f1l + 32768;

__device__ __forceinline__ float gelu_f(float x){
    return 0.5f*x*(1.0f+erff(x*0.70710678118654752f));
}
__device__ __forceinline__ void split_f16(float v, _Float16& hi, _Float16& lo){
    hi = (_Float16)v;
    lo = (_Float16)((v - (float)hi)*LO_SCALE);
}

struct F12 { half8 ah[2], al[2], bh[4], bl[4]; };   // 32x64 wave-tile operand set
struct A4  { half8 h[2], l[2]; };

__device__ __forceinline__ void mm12(const F12& f, f32x4 (&acc)[2][4], f32x4 (&acc2)[2][4]){
    #pragma unroll
    for (int i=0;i<2;i++)
        #pragma unroll
        for (int j=0;j<4;j++){
            acc[i][j]  = __builtin_amdgcn_mfma_f32_16x16x32_f16(f.ah[i], f.bh[j], acc[i][j], 0,0,0);
            acc2[i][j] = __builtin_amdgcn_mfma_f32_16x16x32_f16(f.ah[i], f.bl[j], acc2[i][j],0,0,0);
            acc2[i][j] = __builtin_amdgcn_mfma_f32_16x16x32_f16(f.al[i], f.bh[j], acc2[i][j],0,0,0);
        }
}

// ---------------- tables (split f16) ----------------
__global__ void k_tables(_Float16* __restrict__ Tfh, _Float16* __restrict__ Tfl,
                         _Float16* __restrict__ Tih, _Float16* __restrict__ Til){
    int idx = blockIdx.x*256 + threadIdx.x;   // 4096*256
    int n = idx >> 8, k2 = idx & 255;
    int f = k2 >> 1;
    int m = (n*f) & 4095;
    double th = (double)m * (3.14159265358979323846/2048.0);
    double s, c; sincos(th, &s, &c);
    float vf = (k2&1) ? (float)(-s) : (float)c;
    _Float16 h1,l1; split_f16(vf, h1, l1);
    Tfh[(size_t)k2*4096 + n] = h1;
    Tfl[(size_t)k2*4096 + n] = l1;
    float vi;
    if (k2 == 0)      vi = 1.0f;
    else if (k2 == 1) vi = 0.0f;
    else              vi = vf;
    _Float16 h2,l2; split_f16(vi, h2, l2);
    Tih[(size_t)n*256 + k2] = h2;
    Til[(size_t)n*256 + k2] = l2;
}

__global__ void k_cft_tables(float* __restrict__ Wre, float* __restrict__ Wim,
                             float* __restrict__ wl, float* __restrict__ wr,
                             int* __restrict__ li){
    int idx = blockIdx.x*128 + threadIdx.x;   // 160*128
    if (idx >= LM*MODES) return;
    int lm = idx >> 7;  int f = idx & 127;
    int l = lm / MCH, m = lm % MCH;
    const double PI = 3.14159265358979323846;
    double nodes[8], Tm[8];
    #pragma unroll
    for (int j=0;j<8;j++){
        nodes[j] = -cos((2.0*j+1.0)*PI/16.0);
        Tm[j] = cos((double)m * acos(nodes[j]));
    }
    double wp = (double)f * PI * 0.05;
    double cwre=0.0, cwim=0.0;
    #pragma unroll
    for (int j=0;j<8;j++){
        double sj, cj; sincos(nodes[j]*wp, &sj, &cj);
        cwre += Tm[j]*cj;
        cwim -= Tm[j]*sj;
    }
    cwre *= 0.025; cwim *= 0.025;
    int r = (f*l) % 20;
    double sa = 2.0*PI*(double)r/20.0;
    double shre = cos(sa), shim = -sin(sa);
    Wre[lm*128+f] = (float)(shre*cwre - shim*cwim);
    Wim[lm*128+f] = (float)(shre*cwim + shim*cwre);
    if (f == 0){
        double v = (double)l/20.0 + 0.025*(nodes[m]+1.0);
        int rr = (int)ceil(v*4095.0);
        if (rr > 4095) rr = 4095;
        if (rr < 1) rr = 1;
        int le = rr-1;
        double tl = (double)le/4095.0, tr = (double)rr/4095.0;
        double wrv = (v - tl)/(tr - tl);
        li[lm] = le;
        wl[lm] = (float)(1.0 - wrv);
        wr[lm] = (float)wrv;
    }
}

// sum wA/wB over mode axis
__global__ void k_wsum(const float* __restrict__ wAre, const float* __restrict__ wAim,
                       const float* __restrict__ wBre, const float* __restrict__ wBim,
                       float* __restrict__ out){
    int row  = blockIdx.x*4 + (threadIdx.x>>6);
    int lane = threadIdx.x & 63;
    const float* src = (blockIdx.y==0)?wAre:(blockIdx.y==1)?wAim:(blockIdx.y==2)?wBre:wBim;
    float v = src[(size_t)row*128 + lane] + src[(size_t)row*128 + 64 + lane];
    #pragma unroll
    for (int o=32;o>0;o>>=1) v += __shfl_down(v, o);
    if (lane==0) out[(size_t)blockIdx.y*65536 + row] = v;
}

// pre-split conv & fc1 weights
__global__ void k_wsplit(const float* __restrict__ convW, const float* __restrict__ fc1W,
                         _Float16* __restrict__ cWh, _Float16* __restrict__ cWl,
                         _Float16* __restrict__ f1h, _Float16* __restrict__ f1l){
    int idx = blockIdx.x*256 + threadIdx.x;   // 81920
    if (idx < 65536){
        _Float16 hi,lo; split_f16(convW[idx], hi, lo);
        cWh[idx]=hi; cWl[idx]=lo;
    } else {
        int j = idx - 65536;
        _Float16 hi,lo; split_f16(fc1W[j], hi, lo);
        f1h[j]=hi; f1l[j]=lo;
    }
}

// ---------------- lift: write split h ----------------
__global__ void k_h0(const float* __restrict__ x, const float* __restrict__ w0,
                     const float* __restrict__ b0,
                     _Float16* __restrict__ hh, _Float16* __restrict__ hl){
    int idx = blockIdx.x*256 + threadIdx.x;  // 64*128*512
    int n8 = idx & 511;
    int w  = (idx >> 9) & 127;
    int b  = idx >> 16;
    int n0 = n8*8;
    float w00 = w0[w*2], w01 = w0[w*2+1], bb = b0[w];
    const float* xr = &x[((size_t)b<<12) + n0];
    float4 x0 = *reinterpret_cast<const float4*>(xr);
    float4 x1 = *reinterpret_cast<const float4*>(xr+4);
    float xv[8]={x0.x,x0.y,x0.z,x0.w,x1.x,x1.y,x1.z,x1.w};
    half8 vh, vl;
    #pragma unroll
    for (int q=0;q<8;q++){
        float g = (float)(n0+q) * (1.0f/4095.0f);
        float v = xv[q]*w00 + g*w01 + bb;
        _Float16 hi,lo; split_f16(v,hi,lo);
        vh[q]=hi; vl[q]=lo;
    }
    size_t o = ((size_t)(b*128+w))*4096 + n0;
    *reinterpret_cast<half8*>(&hh[o]) = vh;
    *reinterpret_cast<half8*>(&hl[o]) = vl;
}

// ---------------- CFT magnitude ----------------
__global__ void k_cft(const _Float16* __restrict__ hh, const _Float16* __restrict__ hl,
                      const float* __restrict__ Wre, const float* __restrict__ Wim,
                      const float* __restrict__ wl, const float* __restrict__ wr,
                      const int* __restrict__ li, float* __restrict__ magp){
    int b = blockIdx.x, cg = blockIdx.y;
    int f = threadIdx.x;   // 128
    __shared__ float sig[LM];
    __shared__ float swl[LM], swr[LM];
    __shared__ int   sli[LM];
    for (int s=f; s<LM; s+=128){ swl[s]=wl[s]; swr[s]=wr[s]; sli[s]=li[s]; }
    __syncthreads();
    float acc = 0.f;
    for (int cc=0; cc<16; cc++){
        int c = cg*16 + cc;
        const _Float16* rh = hh + ((size_t)(b*128+c))*4096;
        const _Float16* rl = hl + ((size_t)(b*128+c))*4096;
        for (int s=f; s<LM; s+=128){
            int le = sli[s];
            float v0 = (float)rh[le]   + (float)rl[le]*LO_INV;
            float v1 = (float)rh[le+1] + (float)rl[le+1]*LO_INV;
            sig[s] = swl[s]*v0 + swr[s]*v1;
        }
        __syncthreads();
        float re=0.f, im=0.f;
        #pragma unroll 8
        for (int s=0;s<LM;s++){
            float sv = sig[s];
            re = fmaf(sv, Wre[s*128+f], re);
            im = fmaf(sv, Wim[s*128+f], im);
        }
        acc += sqrtf(re*re+im*im);
        __syncthreads();
    }
    magp[(b*8+cg)*128 + f] = acc;
}

__global__ void k_gate(const float* __restrict__ magp, const float* __restrict__ gW,
                       const float* __restrict__ gB, float* __restrict__ gate, int layer){
    int b = blockIdx.x, w = threadIdx.x;
    __shared__ float ms[128];
    float s = 0.f;
    #pragma unroll
    for (int g=0; g<8; g++) s += magp[(b*8+g)*128 + w];
    ms[w] = s * (1.0f/128.0f);
    __syncthreads();
    const float* gwr = gW + ((size_t)layer*128 + w)*128;
    float a = gB[layer*128 + w];
    #pragma unroll 8
    for (int fq=0; fq<128; fq++) a = fmaf(ms[fq], gwr[fq], a);
    gate[b*128+w] = 1.0f/(1.0f+expf(-a));
}

// ---------------- forward DFT (MFMA, direct-global, no LDS/barriers) ----------------
// F[8192][256] = h[8192][4096] x Tf^T.  grid 256 blocks (bid = nb*64+mb so all 4
// nb-blocks of a row-group share an XCD L2); 4 waves/block, wave tile 32x64.
__global__ __launch_bounds__(256) void k_fdft(
        const _Float16* __restrict__ hh, const _Float16* __restrict__ hl,
        const _Float16* __restrict__ Tfh, const _Float16* __restrict__ Tfl,
        float* __restrict__ F){
    int bid = blockIdx.x;
    int nb = bid >> 6, mb = bid & 63;
    int tid = threadIdx.x, lane = tid & 63, w = tid >> 6;
    int l15 = lane & 15, l4 = lane >> 4;
    int row0 = mb*128 + w*32;
    int col0 = nb*64;
    const _Float16* pah = hh  + (size_t)(row0+l15)*4096 + l4*8;
    const _Float16* pal = hl  + (size_t)(row0+l15)*4096 + l4*8;
    const _Float16* pbh = Tfh + (size_t)(col0+l15)*4096 + l4*8;
    const _Float16* pbl = Tfl + (size_t)(col0+l15)*4096 + l4*8;
    f32x4 acc[2][4] = {}; f32x4 acc2[2][4] = {};
#define LDF(dst,k) do{ \
    _Pragma("unroll") for (int i=0;i<2;i++){ \
        dst.ah[i]=*reinterpret_cast<const half8*>(pah + (size_t)i*65536 + (k)); \
        dst.al[i]=*reinterpret_cast<const half8*>(pal + (size_t)i*65536 + (k)); } \
    _Pragma("unroll") for (int j=0;j<4;j++){ \
        dst.bh[j]=*reinterpret_cast<const half8*>(pbh + (size_t)j*65536 + (k)); \
        dst.bl[j]=*reinterpret_cast<const half8*>(pbl + (size_t)j*65536 + (k)); } }while(0)
    F12 c0, c1;
    LDF(c0, 0); LDF(c1, 32);
    for (int k0 = 0; k0 < 4096; k0 += 64){
        int ka = k0 + 64; ka = (ka < 4096) ? ka : 0;
        int kb = k0 + 96; kb = (kb < 4096) ? kb : 0;
        F12 t0; LDF(t0, ka);
        mm12(c0, acc, acc2);
        F12 t1; LDF(t1, kb);
        mm12(c1, acc, acc2);
        c0 = t0; c1 = t1;
    }
#undef LDF
    #pragma unroll
    for (int i=0;i<2;i++)
        #pragma unroll
        for (int j=0;j<4;j++)
            #pragma unroll
            for (int r=0;r<4;r++){
                int row = row0 + i*16 + l4*4 + r;
                int col = col0 + j*16 + l15;
                F[(size_t)row*256 + col] = acc[i][j][r] + acc2[i][j][r]*LO_INV;
            }
}

// ---------------- mode mix: X = g*(F.wA) + (1-g)*(F.wB), scaled, split ----------------
__global__ __launch_bounds__(256) void k_modemix(const float* __restrict__ F,
        const float* __restrict__ wsum, const float* __restrict__ gate,
        _Float16* __restrict__ Xh, _Float16* __restrict__ Xl, int layer){
    int b = blockIdx.x, og = blockIdx.y;
    __shared__ float Fs[16][256];
    __shared__ float Wa_re[128][8], Wa_im[128][8], Wb_re[128][8], Wb_im[128][8];
    int tid = threadIdx.x;
    for (int e=tid; e<1024; e+=256){
        int i = e>>3, oo = e&7;
        size_t base = ((size_t)layer*128 + i)*128 + og*8 + oo;
        Wa_re[i][oo] = wsum[0*65536 + base];
        Wa_im[i][oo] = wsum[1*65536 + base];
        Wb_re[i][oo] = wsum[2*65536 + base];
        Wb_im[i][oo] = wsum[3*65536 + base];
    }
    int f = tid & 127, half = tid >> 7;
    float pre[4]={},pim[4]={},qre[4]={},qim[4]={};
    for (int i0=0;i0<128;i0+=16){
        for (int e=tid; e<4096; e+=256){
            int ii = e >> 8, k2 = e & 255;
            Fs[ii][k2] = F[((size_t)(b*128 + i0+ii))*256 + k2];
        }
        __syncthreads();
        #pragma unroll
        for (int ii=0; ii<16; ii++){
            float fre = Fs[ii][2*f], fim = Fs[ii][2*f+1];
            int i = i0+ii;
            #pragma unroll
            for (int q=0;q<4;q++){
                int oo = half*4+q;
                float are=Wa_re[i][oo], aim=Wa_im[i][oo];
                float bre=Wb_re[i][oo], bim=Wb_im[i][oo];
                pre[q] = fmaf(fre, are, fmaf(-fim, aim, pre[q]));
                pim[q] = fmaf(fre, aim, fmaf( fim, are, pim[q]));
                qre[q] = fmaf(fre, bre, fmaf(-fim, bim, qre[q]));
                qim[q] = fmaf(fre, bim, fmaf( fim, bre, qim[q]));
            }
        }
        __syncthreads();
    }
    #pragma unroll
    for (int q=0;q<4;q++){
        int o = og*8 + half*4 + q;
        float g = gate[b*128+o];
        float xre = g*pre[q] + (1.f-g)*qre[q];
        float xim = g*pim[q] + (1.f-g)*qim[q];
        float s = (f==0) ? (1.0f/4096.0f) : (2.0f/4096.0f);
        xre *= s; xim *= s;
        if (f==0) xim = 0.f;
        size_t base = ((size_t)(b*128+o))*256 + 2*f;
        _Float16 h1,l1; split_f16(xre,h1,l1); Xh[base]=h1;   Xl[base]=l1;
        _Float16 h2,l2; split_f16(xim,h2,l2); Xh[base+1]=h2; Xl[base+1]=l2;
    }
}

// ---------------- fused in-place irfft + conv + bias + gelu ----------------
// LDS only for the h transpose (staged once, 1 barrier); convW/X/Ti direct-global.
// block: (n-tile, b), 4 waves, wave tile 32(o) x 64(n).
__global__ __launch_bounds__(256) void k_flayer(
    const _Float16* __restrict__ Xh, const _Float16* __restrict__ Xl,
    const _Float16* __restrict__ Tih, const _Float16* __restrict__ Til,
    const _Float16* __restrict__ cWh, const _Float16* __restrict__ cWl,
    const float* __restrict__ convB,
    _Float16* __restrict__ hh, _Float16* __restrict__ hl,
    int layer, int applyGelu){
    __shared__ _Float16 Bch[64][136], Bcl[64][136];
    int n0 = blockIdx.x*64;
    int b  = blockIdx.y;
    int tid = threadIdx.x, lane = tid & 63, w = tid >> 6;
    int l15 = lane & 15, l4 = lane >> 4;
    int o0 = w*32;
    // stage transposed h tile (lane-per-channel, ~2-way on writes)
    {
        int c = tid & 127, nh = tid >> 7;
        const _Float16* rh = hh + ((size_t)(b*128+c))*4096 + n0 + nh*32;
        const _Float16* rl = hl + ((size_t)(b*128+c))*4096 + n0 + nh*32;
        #pragma unroll
        for (int j=0;j<4;j++){
            half8 vhv = *reinterpret_cast<const half8*>(rh + j*8);
            half8 vlv = *reinterpret_cast<const half8*>(rl + j*8);
            #pragma unroll
            for (int q=0;q<8;q++){
                int n = nh*32 + j*8 + q;
                Bch[n][c] = vhv[q];
                Bcl[n][c] = vlv[q];
            }
        }
    }
    __syncthreads();   // only barrier in the kernel
    f32x4 acc[2][4] = {}; f32x4 acc2[2][4] = {};
    // ---- phase 1: conv, K=128; A = convW direct global, B = LDS ----
    const _Float16* pach = cWh + (size_t)layer*16384 + (size_t)(o0+l15)*128 + l4*8;
    const _Float16* pacl = cWl + (size_t)layer*16384 + (size_t)(o0+l15)*128 + l4*8;
#define LDA(dst,k) do{ \
    dst.h[0]=*reinterpret_cast<const half8*>(pach + (k)); \
    dst.h[1]=*reinterpret_cast<const half8*>(pach + 2048 + (k)); \
    dst.l[0]=*reinterpret_cast<const half8*>(pacl + (k)); \
    dst.l[1]=*reinterpret_cast<const half8*>(pacl + 2048 + (k)); }while(0)
#define MM1(a,k0) do{ \
    _Pragma("unroll") for (int j=0;j<4;j++){ \
        half8 bh=*reinterpret_cast<const half8*>(&Bch[j*16+l15][(k0)+l4*8]); \
        half8 bl=*reinterpret_cast<const half8*>(&Bcl[j*16+l15][(k0)+l4*8]); \
        _Pragma("unroll") for (int i=0;i<2;i++){ \
            acc[i][j]  = __builtin_amdgcn_mfma_f32_16x16x32_f16(a.h[i], bh, acc[i][j], 0,0,0); \
            acc2[i][j] = __builtin_amdgcn_mfma_f32_16x16x32_f16(a.h[i], bl, acc2[i][j],0,0,0); \
            acc2[i][j] = __builtin_amdgcn_mfma_f32_16x16x32_f16(a.l[i], bh, acc2[i][j],0,0,0); } } }while(0)
    {
        A4 a0,a1,a2,a3;
        LDA(a0,0); LDA(a1,32); LDA(a2,64); LDA(a3,96);
        MM1(a0,0); MM1(a1,32); MM1(a2,64); MM1(a3,96);
    }
#undef LDA
#undef MM1
    // ---- phase 2: irfft, K=256; A = X, B = Ti, both direct global ----
    const _Float16* pxh = Xh + ((size_t)(b*128+o0+l15))*256 + l4*8;
    const _Float16* pxl = Xl + ((size_t)(b*128+o0+l15))*256 + l4*8;
    const _Float16* pth = Tih + (size_t)(n0+l15)*256 + l4*8;
    const _Float16* ptl = Til + (size_t)(n0+l15)*256 + l4*8;
#define LD2(dst,k) do{ \
    _Pragma("unroll") for (int i=0;i<2;i++){ \
        dst.ah[i]=*reinterpret_cast<const half8*>(pxh + i*4096 + (k)); \
        dst.al[i]=*reinterpret_cast<const half8*>(pxl + i*4096 + (k)); } \
    _Pragma("unroll") for (int j=0;j<4;j++){ \
        dst.bh[j]=*reinterpret_cast<const half8*>(pth + j*4096 + (k)); \
        dst.bl[j]=*reinterpret_cast<const half8*>(ptl + j*4096 + (k)); } }while(0)
    {
        F12 c0, c1;
        LD2(c0, 0); LD2(c1, 32);
        #pragma unroll
        for (int k0=0; k0<256; k0+=64){
            F12 t0, t1;
            if (k0 < 192) LD2(t0, k0+64);
            mm12(c0, acc, acc2);
            if (k0 < 192) LD2(t1, k0+96);
            mm12(c1, acc, acc2);
            c0 = t0; c1 = t1;
        }
    }
#undef LD2
    // epilogue: bias (+gelu), split, write back in place
    #pragma unroll
    for (int i=0;i<2;i++)
        #pragma unroll
        for (int j=0;j<4;j++)
            #pragma unroll
            for (int r=0;r<4;r++){
                int o = o0 + i*16 + l4*4 + r;
                int n = n0 + j*16 + l15;
                float v = acc[i][j][r] + acc2[i][j][r]*LO_INV + convB[layer*128+o];
                if (applyGelu) v = gelu_f(v);
                _Float16 hi,lo; split_f16(v,hi,lo);
                size_t oi = ((size_t)(b*128+o))*4096 + n;
                hh[oi] = hi; hl[oi] = lo;
            }
}

// ---------------- head (MFMA, direct-global fc1W, 1 staging barrier) ----------------
__global__ __launch_bounds__(256) void k_head(
        const _Float16* __restrict__ hh, const _Float16* __restrict__ hl,
        const _Float16* __restrict__ f1h, const _Float16* __restrict__ f1l,
        const float* __restrict__ fc1b,
        const float* __restrict__ fc2W, const float* __restrict__ fc2b,
        float* __restrict__ out){
    __shared__ _Float16 Bch[64][136], Bcl[64][136];
    __shared__ float red[16][64];
    int n0 = blockIdx.x*64;
    int b  = blockIdx.y;
    int tid = threadIdx.x, lane = tid & 63, w = tid >> 6;
    int l15 = lane & 15, l4 = lane >> 4;
    int j0 = w*32;
    {
        int c = tid & 127, nh = tid >> 7;
        const _Float16* rh = hh + ((size_t)(b*128+c))*4096 + n0 + nh*32;
        const _Float16* rl = hl + ((size_t)(b*128+c))*4096 + n0 + nh*32;
        #pragma unroll
        for (int j=0;j<4;j++){
            half8 vhv = *reinterpret_cast<const half8*>(rh + j*8);
            half8 vlv = *reinterpret_cast<const half8*>(rl + j*8);
            #pragma unroll
            for (int q=0;q<8;q++){
                int n = nh*32 + j*8 + q;
                Bch[n][c] = vhv[q];
                Bcl[n][c] = vlv[q];
            }
        }
    }
    __syncthreads();
    f32x4 acc[2][4] = {}; f32x4 acc2[2][4] = {};
    const _Float16* pah = f1h + (size_t)(j0+l15)*128 + l4*8;
    const _Float16* pal = f1l + (size_t)(j0+l15)*128 + l4*8;
#define LDA(dst,k) do{ \
    dst.h[0]=*reinterpret_cast<const half8*>(pah + (k)); \
    dst.h[1]=*reinterpret_cast<const half8*>(pah + 2048 + (k)); \
    dst.l[0]=*reinterpret_cast<const half8*>(pal + (k)); \
    dst.l[1]=*reinterpret_cast<const half8*>(pal + 2048 + (k)); }while(0)
#define MM1(a,k0) do{ \
    _Pragma("unroll") for (int j=0;j<4;j++){ \
        half8 bh=*reinterpret_cast<const half8*>(&Bch[j*16+l15][(k0)+l4*8]); \
        half8 bl=*reinterpret_cast<const half8*>(&Bcl[j*16+l15][(k0)+l4*8]); \
        _Pragma("unroll") for (int i=0;i<2;i++){ \
            acc[i][j]  = __builtin_amdgcn_mfma_f32_16x16x32_f16(a.h[i], bh, acc[i][j], 0,0,0); \
            acc2[i][j] = __builtin_amdgcn_mfma_f32_16x16x32_f16(a.h[i], bl, acc2[i][j],0,0,0); \
            acc2[i][j] = __builtin_amdgcn_mfma_f32_16x16x32_f16(a.l[i], bh, acc2[i][j],0,0,0); } } }while(0)
    {
        A4 a0,a1,a2,a3;
        LDA(a0,0); LDA(a1,32); LDA(a2,64); LDA(a3,96);
        MM1(a0,0); MM1(a1,32); MM1(a2,64); MM1(a3,96);
    }
#undef LDA
#undef MM1
    float part[4];
    #pragma unroll
    for (int j=0;j<4;j++) part[j] = 0.f;
    #pragma unroll
    for (int i=0;i<2;i++){
        #pragma unroll
        for (int r=0;r<4;r++){
            int jj = j0 + i*16 + l4*4 + r;
            float b1 = fc1b[jj];
            float w2 = fc2W[jj];
            #pragma unroll
            for (int j=0;j<4;j++){
                float v = acc[i][j][r] + acc2[i][j][r]*LO_INV + b1;
                part[j] = fmaf(w2, gelu_f(v), part[j]);
            }
        }
    }
    #pragma unroll
    for (int j=0;j<4;j++) red[w*4+l4][j*16+l15] = part[j];
    __syncthreads();
    if (tid < 64){
        float s = fc2b[0];
        #pragma unroll
        for (int r=0;r<16;r++) s += red[r][tid];
        out[((size_t)b<<12) + n0 + tid] = s;
    }
}

extern "C" void kernel_launch(void* const* d_in, const int* in_sizes, int n_in,
                              void* d_out, int out_size, void* d_ws, size_t ws_size,
                              hipStream_t stream) {
    const float* x     = (const float*)d_in[0];
    const float* fc0W  = (const float*)d_in[1];
    const float* fc0b  = (const float*)d_in[2];
    const float* gateW = (const float*)d_in[3];
    const float* gateB = (const float*)d_in[4];
    const float* wAre  = (const float*)d_in[5];
    const float* wAim  = (const float*)d_in[6];
    const float* wBre  = (const float*)d_in[7];
    const float* wBim  = (const float*)d_in[8];
    const float* convW = (const float*)d_in[9];
    const float* convB = (const float*)d_in[10];
    const float* fc1W  = (const float*)d_in[11];
    const float* fc1b  = (const float*)d_in[12];
    const float* fc2W  = (const float*)d_in[13];
    const float* fc2b  = (const float*)d_in[14];
    float* out = (float*)d_out;
    char*  wsb = (char*)d_ws;

    float* F    = (float*)(wsb + BY_F);
    float* wsum = (float*)(wsb + BY_wsum);
    float* Wcre = (float*)(wsb + BY_Wcre);
    float* Wcim = (float*)(wsb + BY_Wcim);
    float* wl   = (float*)(wsb + BY_wl);
    float* wr   = (float*)(wsb + BY_wr);
    int*   li   = (int*)(wsb + BY_li);
    float* magp = (float*)(wsb + BY_magp);
    float* gate = (float*)(wsb + BY_gate);
    _Float16* hh  = (_Float16*)(wsb + BY_hh);
    _Float16* hl  = (_Float16*)(wsb + BY_hl);
    _Float16* Tfh = (_Float16*)(wsb + BY_Tfh);
    _Float16* Tfl = (_Float16*)(wsb + BY_Tfl);
    _Float16* Tih = (_Float16*)(wsb + BY_Tih);
    _Float16* Til = (_Float16*)(wsb + BY_Til);
    _Float16* Xh  = (_Float16*)(wsb + BY_Xh);
    _Float16* Xl  = (_Float16*)(wsb + BY_Xl);
    _Float16* cWh = (_Float16*)(wsb + BY_cWh);
    _Float16* cWl = (_Float16*)(wsb + BY_cWl);
    _Float16* f1h = (_Float16*)(wsb + BY_f1h);
    _Float16* f1l = (_Float16*)(wsb + BY_f1l);

    k_tables<<<4096, 256, 0, stream>>>(Tfh, Tfl, Tih, Til);
    k_cft_tables<<<160, 128, 0, stream>>>(Wcre, Wcim, wl, wr, li);
    k_wsum<<<dim3(16384,4), 256, 0, stream>>>(wAre, wAim, wBre, wBim, wsum);
    k_wsplit<<<320, 256, 0, stream>>>(convW, fc1W, cWh, cWl, f1h, f1l);
    k_h0<<<16384, 256, 0, stream>>>(x, fc0W, fc0b, hh, hl);

    for (int layer=0; layer<4; layer++){
        k_cft<<<dim3(64,8), 128, 0, stream>>>(hh, hl, Wcre, Wcim, wl, wr, li, magp);
        k_gate<<<64, 128, 0, stream>>>(magp, gateW, gateB, gate, layer);
        k_fdft<<<256, 256, 0, stream>>>(hh, hl, Tfh, Tfl, F);
        k_modemix<<<dim3(64,16), 256, 0, stream>>>(F, wsum, gate, Xh, Xl, layer);
        k_flayer<<<dim3(64,64), 256, 0, stream>>>(Xh, Xl, Tih, Til, cWh, cWl, convB,
                                                  hh, hl, layer, layer<3 ? 1:0);
    }
    k_head<<<dim3(64,64), 256, 0, stream>>>(hh, hl, f1h, f1l, fc1b, fc2W, fc2b, out);
    (void)in_sizes; (void)n_in; (void)out_size; (void)ws_size;
}

// Round 7
// 1623.977 us; speedup vs baseline: 1.5519x; 1.5519x over previous
//
#include <hip/hip_runtime.h>
#include <math.h>

#define B_SZ 64
#define WID 128
#define NPT 4096
#define MODES 128
#define LSEG 20
#define MCH 8
#define LM 160   // LSEG*MCH

typedef _Float16 half8 __attribute__((ext_vector_type(8)));
typedef float f32x4 __attribute__((ext_vector_type(4)));

#define LO_SCALE 2048.0f
#define LO_INV   (1.0f/2048.0f)

// ---------------- workspace layout (bytes), total ~161.3 MB ----------------
static constexpr size_t BY_F    = 0;                       // fp32 [8192][256]
static constexpr size_t BY_wsum = BY_F + 8388608;          // fp32 [4][4][128][128]
static constexpr size_t BY_Wcre = BY_wsum + 1048576;       // fp32 [160][128]
static constexpr size_t BY_Wcim = BY_Wcre + 81920;
static constexpr size_t BY_wl   = BY_Wcim + 81920;         // fp32 [160] (pad)
static constexpr size_t BY_wr   = BY_wl + 1024;
static constexpr size_t BY_li   = BY_wr + 1024;            // int [160]
static constexpr size_t BY_magp = BY_li + 1024;            // fp32 [64][8][128]
static constexpr size_t BY_gate = BY_magp + 262144;        // fp32 [64][128]
static constexpr size_t BY_hh   = BY_gate + 32768;         // f16 [64][128][4096] split-hi
static constexpr size_t BY_hl   = BY_hh + 67108864;        // f16 split-lo
static constexpr size_t BY_Tfh  = BY_hl + 67108864;        // f16 [256][4096]
static constexpr size_t BY_Tfl  = BY_Tfh + 2097152;
static constexpr size_t BY_Tih  = BY_Tfl + 2097152;        // f16 [4096][256]
static constexpr size_t BY_Til  = BY_Tih + 2097152;
static constexpr size_t BY_Xh   = BY_Til + 2097152;        // f16 [64][128][256]
static constexpr size_t BY_Xl   = BY_Xh + 4194304;
static constexpr size_t BY_cWh  = BY_Xl + 4194304;         // f16 [4][128][128]
static constexpr size_t BY_cWl  = BY_cWh + 131072;
static constexpr size_t BY_f1h  = BY_cWl + 131072;         // f16 [128][128]
static constexpr size_t BY_f1l  = BY_f1h + 32768;
static constexpr size_t BY_end  = BY_f1l + 32768;

__device__ __forceinline__ float gelu_f(float x){
    return 0.5f*x*(1.0f+erff(x*0.70710678118654752f));
}
__device__ __forceinline__ void split_f16(float v, _Float16& hi, _Float16& lo){
    hi = (_Float16)v;
    lo = (_Float16)((v - (float)hi)*LO_SCALE);
}

// ---------------- tables (split f16) ----------------
__global__ void k_tables(_Float16* __restrict__ Tfh, _Float16* __restrict__ Tfl,
                         _Float16* __restrict__ Tih, _Float16* __restrict__ Til){
    int idx = blockIdx.x*256 + threadIdx.x;   // 4096*256
    int n = idx >> 8, k2 = idx & 255;
    int f = k2 >> 1;
    int m = (n*f) & 4095;
    double th = (double)m * (3.14159265358979323846/2048.0);
    double s, c; sincos(th, &s, &c);
    float vf = (k2&1) ? (float)(-s) : (float)c;
    _Float16 h1,l1; split_f16(vf, h1, l1);
    Tfh[(size_t)k2*4096 + n] = h1;
    Tfl[(size_t)k2*4096 + n] = l1;
    float vi;
    if (k2 == 0)      vi = 1.0f;
    else if (k2 == 1) vi = 0.0f;
    else              vi = vf;
    _Float16 h2,l2; split_f16(vi, h2, l2);
    Tih[(size_t)n*256 + k2] = h2;
    Til[(size_t)n*256 + k2] = l2;
}

__global__ void k_cft_tables(float* __restrict__ Wre, float* __restrict__ Wim,
                             float* __restrict__ wl, float* __restrict__ wr,
                             int* __restrict__ li){
    int idx = blockIdx.x*128 + threadIdx.x;   // 160*128
    if (idx >= LM*MODES) return;
    int lm = idx >> 7;  int f = idx & 127;
    int l = lm / MCH, m = lm % MCH;
    const double PI = 3.14159265358979323846;
    double nodes[8], Tm[8];
    #pragma unroll
    for (int j=0;j<8;j++){
        nodes[j] = -cos((2.0*j+1.0)*PI/16.0);
        Tm[j] = cos((double)m * acos(nodes[j]));
    }
    double wp = (double)f * PI * 0.05;
    double cwre=0.0, cwim=0.0;
    #pragma unroll
    for (int j=0;j<8;j++){
        double sj, cj; sincos(nodes[j]*wp, &sj, &cj);
        cwre += Tm[j]*cj;
        cwim -= Tm[j]*sj;
    }
    cwre *= 0.025; cwim *= 0.025;
    int r = (f*l) % 20;
    double sa = 2.0*PI*(double)r/20.0;
    double shre = cos(sa), shim = -sin(sa);
    Wre[lm*128+f] = (float)(shre*cwre - shim*cwim);
    Wim[lm*128+f] = (float)(shre*cwim + shim*cwre);
    if (f == 0){
        double v = (double)l/20.0 + 0.025*(nodes[m]+1.0);
        int rr = (int)ceil(v*4095.0);
        if (rr > 4095) rr = 4095;
        if (rr < 1) rr = 1;
        int le = rr-1;
        double tl = (double)le/4095.0, tr = (double)rr/4095.0;
        double wrv = (v - tl)/(tr - tl);
        li[lm] = le;
        wl[lm] = (float)(1.0 - wrv);
        wr[lm] = (float)wrv;
    }
}

// sum wA/wB over mode axis
__global__ void k_wsum(const float* __restrict__ wAre, const float* __restrict__ wAim,
                       const float* __restrict__ wBre, const float* __restrict__ wBim,
                       float* __restrict__ out){
    int row  = blockIdx.x*4 + (threadIdx.x>>6);
    int lane = threadIdx.x & 63;
    const float* src = (blockIdx.y==0)?wAre:(blockIdx.y==1)?wAim:(blockIdx.y==2)?wBre:wBim;
    float v = src[(size_t)row*128 + lane] + src[(size_t)row*128 + 64 + lane];
    #pragma unroll
    for (int o=32;o>0;o>>=1) v += __shfl_down(v, o);
    if (lane==0) out[(size_t)blockIdx.y*65536 + row] = v;
}

// pre-split conv & fc1 weights
__global__ void k_wsplit(const float* __restrict__ convW, const float* __restrict__ fc1W,
                         _Float16* __restrict__ cWh, _Float16* __restrict__ cWl,
                         _Float16* __restrict__ f1h, _Float16* __restrict__ f1l){
    int idx = blockIdx.x*256 + threadIdx.x;   // 81920
    if (idx < 65536){
        _Float16 hi,lo; split_f16(convW[idx], hi, lo);
        cWh[idx]=hi; cWl[idx]=lo;
    } else {
        int j = idx - 65536;
        _Float16 hi,lo; split_f16(fc1W[j], hi, lo);
        f1h[j]=hi; f1l[j]=lo;
    }
}

// ---------------- lift: write split h ----------------
__global__ void k_h0(const float* __restrict__ x, const float* __restrict__ w0,
                     const float* __restrict__ b0,
                     _Float16* __restrict__ hh, _Float16* __restrict__ hl){
    int idx = blockIdx.x*256 + threadIdx.x;  // 64*128*512
    int n8 = idx & 511;
    int w  = (idx >> 9) & 127;
    int b  = idx >> 16;
    int n0 = n8*8;
    float w00 = w0[w*2], w01 = w0[w*2+1], bb = b0[w];
    const float* xr = &x[((size_t)b<<12) + n0];
    float4 x0 = *reinterpret_cast<const float4*>(xr);
    float4 x1 = *reinterpret_cast<const float4*>(xr+4);
    float xv[8]={x0.x,x0.y,x0.z,x0.w,x1.x,x1.y,x1.z,x1.w};
    half8 vh, vl;
    #pragma unroll
    for (int q=0;q<8;q++){
        float g = (float)(n0+q) * (1.0f/4095.0f);
        float v = xv[q]*w00 + g*w01 + bb;
        _Float16 hi,lo; split_f16(v,hi,lo);
        vh[q]=hi; vl[q]=lo;
    }
    size_t o = ((size_t)(b*128+w))*4096 + n0;
    *reinterpret_cast<half8*>(&hh[o]) = vh;
    *reinterpret_cast<half8*>(&hl[o]) = vl;
}

// ---------------- CFT magnitude ----------------
__global__ void k_cft(const _Float16* __restrict__ hh, const _Float16* __restrict__ hl,
                      const float* __restrict__ Wre, const float* __restrict__ Wim,
                      const float* __restrict__ wl, const float* __restrict__ wr,
                      const int* __restrict__ li, float* __restrict__ magp){
    int b = blockIdx.x, cg = blockIdx.y;
    int f = threadIdx.x;   // 128
    __shared__ float sig[LM];
    __shared__ float swl[LM], swr[LM];
    __shared__ int   sli[LM];
    for (int s=f; s<LM; s+=128){ swl[s]=wl[s]; swr[s]=wr[s]; sli[s]=li[s]; }
    __syncthreads();
    float acc = 0.f;
    for (int cc=0; cc<16; cc++){
        int c = cg*16 + cc;
        const _Float16* rh = hh + ((size_t)(b*128+c))*4096;
        const _Float16* rl = hl + ((size_t)(b*128+c))*4096;
        for (int s=f; s<LM; s+=128){
            int le = sli[s];
            float v0 = (float)rh[le]   + (float)rl[le]*LO_INV;
            float v1 = (float)rh[le+1] + (float)rl[le+1]*LO_INV;
            sig[s] = swl[s]*v0 + swr[s]*v1;
        }
        __syncthreads();
        float re=0.f, im=0.f;
        #pragma unroll 8
        for (int s=0;s<LM;s++){
            float sv = sig[s];
            re = fmaf(sv, Wre[s*128+f], re);
            im = fmaf(sv, Wim[s*128+f], im);
        }
        acc += sqrtf(re*re+im*im);
        __syncthreads();
    }
    magp[(b*8+cg)*128 + f] = acc;
}

__global__ void k_gate(const float* __restrict__ magp, const float* __restrict__ gW,
                       const float* __restrict__ gB, float* __restrict__ gate, int layer){
    int b = blockIdx.x, w = threadIdx.x;
    __shared__ float ms[128];
    float s = 0.f;
    #pragma unroll
    for (int g=0; g<8; g++) s += magp[(b*8+g)*128 + w];
    ms[w] = s * (1.0f/128.0f);
    __syncthreads();
    const float* gwr = gW + ((size_t)layer*128 + w)*128;
    float a = gB[layer*128 + w];
    #pragma unroll 8
    for (int fq=0; fq<128; fq++) a = fmaf(ms[fq], gwr[fq], a);
    gate[b*128+w] = 1.0f/(1.0f+expf(-a));
}

// ---------------- forward DFT (MFMA, double-buffered LDS, 1 barrier/chunk) ----------------
__global__ __launch_bounds__(256) void k_fdft(
        const _Float16* __restrict__ hh, const _Float16* __restrict__ hl,
        const _Float16* __restrict__ Tfh, const _Float16* __restrict__ Tfl,
        float* __restrict__ F){
    __shared__ _Float16 Ah[2][64][40], Al[2][64][40], Bh[2][64][40], Bl[2][64][40];
    int id = blockIdx.x;
    int swz = (id & 7)*64 + (id >> 3);        // bijective for 512
    int bx = swz & 3, by = swz >> 2;
    int col0 = bx*64, row0 = by*64;
    int tid = threadIdx.x;
    int lane = tid & 63, w = tid >> 6;
    int wr = (w>>1)*32, wc = (w&1)*32;
    int l15 = lane & 15, l4 = lane >> 4;
    f32x4 acc[2][2] = {}; f32x4 acc2[2][2] = {};
    int srow = tid >> 2, sseg = tid & 3;
    const _Float16* pa_h = hh  + (size_t)(row0+srow)*4096 + sseg*8;
    const _Float16* pa_l = hl  + (size_t)(row0+srow)*4096 + sseg*8;
    const _Float16* pb_h = Tfh + (size_t)(col0+srow)*4096 + sseg*8;
    const _Float16* pb_l = Tfl + (size_t)(col0+srow)*4096 + sseg*8;
    // prologue: stage k=0 into buf 0
    half8 ra_h = *reinterpret_cast<const half8*>(pa_h);
    half8 ra_l = *reinterpret_cast<const half8*>(pa_l);
    half8 rb_h = *reinterpret_cast<const half8*>(pb_h);
    half8 rb_l = *reinterpret_cast<const half8*>(pb_l);
    *reinterpret_cast<half8*>(&Ah[0][srow][sseg*8]) = ra_h;
    *reinterpret_cast<half8*>(&Al[0][srow][sseg*8]) = ra_l;
    *reinterpret_cast<half8*>(&Bh[0][srow][sseg*8]) = rb_h;
    *reinterpret_cast<half8*>(&Bl[0][srow][sseg*8]) = rb_l;
    __syncthreads();
    for (int it = 0; it < 128; ++it){
        int cur = it & 1;
        if (it < 127){                       // issue next chunk's loads early
            int k = (it+1)*32;
            ra_h = *reinterpret_cast<const half8*>(pa_h + k);
            ra_l = *reinterpret_cast<const half8*>(pa_l + k);
            rb_h = *reinterpret_cast<const half8*>(pb_h + k);
            rb_l = *reinterpret_cast<const half8*>(pb_l + k);
        }
        half8 fah[2], fal[2], fbh[2], fbl[2];
        #pragma unroll
        for (int i=0;i<2;i++){
            fah[i] = *reinterpret_cast<const half8*>(&Ah[cur][wr + i*16 + l15][l4*8]);
            fal[i] = *reinterpret_cast<const half8*>(&Al[cur][wr + i*16 + l15][l4*8]);
            fbh[i] = *reinterpret_cast<const half8*>(&Bh[cur][wc + i*16 + l15][l4*8]);
            fbl[i] = *reinterpret_cast<const half8*>(&Bl[cur][wc + i*16 + l15][l4*8]);
        }
        #pragma unroll
        for (int i=0;i<2;i++)
            #pragma unroll
            for (int j=0;j<2;j++){
                acc[i][j]  = __builtin_amdgcn_mfma_f32_16x16x32_f16(fah[i], fbh[j], acc[i][j], 0,0,0);
                acc2[i][j] = __builtin_amdgcn_mfma_f32_16x16x32_f16(fah[i], fbl[j], acc2[i][j],0,0,0);
                acc2[i][j] = __builtin_amdgcn_mfma_f32_16x16x32_f16(fal[i], fbh[j], acc2[i][j],0,0,0);
            }
        if (it < 127){                       // write prefetched chunk into other buf
            int nxt = cur ^ 1;
            *reinterpret_cast<half8*>(&Ah[nxt][srow][sseg*8]) = ra_h;
            *reinterpret_cast<half8*>(&Al[nxt][srow][sseg*8]) = ra_l;
            *reinterpret_cast<half8*>(&Bh[nxt][srow][sseg*8]) = rb_h;
            *reinterpret_cast<half8*>(&Bl[nxt][srow][sseg*8]) = rb_l;
        }
        __syncthreads();                     // single barrier per chunk
    }
    #pragma unroll
    for (int i=0;i<2;i++)
        #pragma unroll
        for (int j=0;j<2;j++)
            #pragma unroll
            for (int r=0;r<4;r++){
                int row = row0 + wr + i*16 + l4*4 + r;
                int col = col0 + wc + j*16 + l15;
                F[(size_t)row*256 + col] = acc[i][j][r] + acc2[i][j][r]*LO_INV;
            }
}

// ---------------- mode mix: X = g*(F.wA) + (1-g)*(F.wB), scaled, split ----------------
__global__ __launch_bounds__(256) void k_modemix(const float* __restrict__ F,
        const float* __restrict__ wsum, const float* __restrict__ gate,
        _Float16* __restrict__ Xh, _Float16* __restrict__ Xl, int layer){
    int b = blockIdx.x, og = blockIdx.y;
    __shared__ float Fs[16][256];
    __shared__ float Wa_re[128][8], Wa_im[128][8], Wb_re[128][8], Wb_im[128][8];
    int tid = threadIdx.x;
    for (int e=tid; e<1024; e+=256){
        int i = e>>3, oo = e&7;
        size_t base = ((size_t)layer*128 + i)*128 + og*8 + oo;
        Wa_re[i][oo] = wsum[0*65536 + base];
        Wa_im[i][oo] = wsum[1*65536 + base];
        Wb_re[i][oo] = wsum[2*65536 + base];
        Wb_im[i][oo] = wsum[3*65536 + base];
    }
    int f = tid & 127, half = tid >> 7;
    float pre[4]={},pim[4]={},qre[4]={},qim[4]={};
    for (int i0=0;i0<128;i0+=16){
        for (int e=tid; e<4096; e+=256){
            int ii = e >> 8, k2 = e & 255;
            Fs[ii][k2] = F[((size_t)(b*128 + i0+ii))*256 + k2];
        }
        __syncthreads();
        #pragma unroll
        for (int ii=0; ii<16; ii++){
            float fre = Fs[ii][2*f], fim = Fs[ii][2*f+1];
            int i = i0+ii;
            #pragma unroll
            for (int q=0;q<4;q++){
                int oo = half*4+q;
                float are=Wa_re[i][oo], aim=Wa_im[i][oo];
                float bre=Wb_re[i][oo], bim=Wb_im[i][oo];
                pre[q] = fmaf(fre, are, fmaf(-fim, aim, pre[q]));
                pim[q] = fmaf(fre, aim, fmaf( fim, are, pim[q]));
                qre[q] = fmaf(fre, bre, fmaf(-fim, bim, qre[q]));
                qim[q] = fmaf(fre, bim, fmaf( fim, bre, qim[q]));
            }
        }
        __syncthreads();
    }
    #pragma unroll
    for (int q=0;q<4;q++){
        int o = og*8 + half*4 + q;
        float g = gate[b*128+o];
        float xre = g*pre[q] + (1.f-g)*qre[q];
        float xim = g*pim[q] + (1.f-g)*qim[q];
        float s = (f==0) ? (1.0f/4096.0f) : (2.0f/4096.0f);
        xre *= s; xim *= s;
        if (f==0) xim = 0.f;
        size_t base = ((size_t)(b*128+o))*256 + 2*f;
        _Float16 h1,l1; split_f16(xre,h1,l1); Xh[base]=h1;   Xl[base]=l1;
        _Float16 h2,l2; split_f16(xim,h2,l2); Xh[base+1]=h2; Xl[base+1]=l2;
    }
}

// ---------------- fused in-place irfft + conv + bias + gelu (MFMA, dbuf phase 2) ----------------
__global__ __launch_bounds__(256) void k_flayer(
    const _Float16* __restrict__ Xh, const _Float16* __restrict__ Xl,
    const _Float16* __restrict__ Tih, const _Float16* __restrict__ Til,
    const _Float16* __restrict__ cWh, const _Float16* __restrict__ cWl,
    const float* __restrict__ convB,
    _Float16* __restrict__ hh, _Float16* __restrict__ hl,
    int layer, int applyGelu){
    __shared__ char smem[61440];
    // phase 1: h-transpose tile + conv-weight staging
    _Float16 (*Bch)[136] = (_Float16(*)[136])(smem);            // 17,408 B
    _Float16 (*Bcl)[136] = (_Float16(*)[136])(smem + 17408);    // 17,408 B
    _Float16 (*A1h)[40]  = (_Float16(*)[40])(smem + 34816);     // [128][40]
    _Float16 (*A1l)[40]  = (_Float16(*)[40])(smem + 45056);
    // phase 2: double-buffered X/Ti tiles (alias over Bch after phase 1)
    _Float16 (*A2h)[128][40] = (_Float16(*)[128][40])(smem);          // [2][128][40]
    _Float16 (*A2l)[128][40] = (_Float16(*)[128][40])(smem + 20480);
    _Float16 (*B2h)[64][40]  = (_Float16(*)[64][40])(smem + 40960);   // [2][64][40]
    _Float16 (*B2l)[64][40]  = (_Float16(*)[64][40])(smem + 51200);
    int n0 = blockIdx.x*64;
    int b  = blockIdx.y;
    int tid = threadIdx.x, lane = tid & 63, w = tid >> 6;
    int l15 = lane & 15, l4 = lane >> 4;
    int o0 = w*32;
    f32x4 acc[2][4] = {}; f32x4 acc2[2][4] = {};
    // stage transposed h tile (lane-per-channel)
    {
        int c = tid & 127, nh = tid >> 7;
        const _Float16* rh = hh + ((size_t)(b*128+c))*4096 + n0 + nh*32;
        const _Float16* rl = hl + ((size_t)(b*128+c))*4096 + n0 + nh*32;
        #pragma unroll
        for (int j=0;j<4;j++){
            half8 vhv = *reinterpret_cast<const half8*>(rh + j*8);
            half8 vlv = *reinterpret_cast<const half8*>(rl + j*8);
            #pragma unroll
            for (int q=0;q<8;q++){
                int n = nh*32 + j*8 + q;
                Bch[n][c] = vhv[q];
                Bcl[n][c] = vlv[q];
            }
        }
    }
    __syncthreads();
    int so2 = tid >> 2, sseg = tid & 3;
    // ---- phase 1: pointwise conv, K=128 (single-buffered, small) ----
    const _Float16* cwh = cWh + (size_t)layer*16384;
    const _Float16* cwl = cWl + (size_t)layer*16384;
    for (int k0=0;k0<128;k0+=32){
        #pragma unroll
        for (int p=0;p<2;p++){
            int o = p*64 + so2;
            *reinterpret_cast<half8*>(&A1h[o][sseg*8]) =
                *reinterpret_cast<const half8*>(&cwh[(size_t)o*128 + k0 + sseg*8]);
            *reinterpret_cast<half8*>(&A1l[o][sseg*8]) =
                *reinterpret_cast<const half8*>(&cwl[(size_t)o*128 + k0 + sseg*8]);
        }
        __syncthreads();
        half8 ah[2],al[2],bh[4],bl[4];
        #pragma unroll
        for (int i=0;i<2;i++){
            ah[i] = *reinterpret_cast<const half8*>(&A1h[o0+i*16+l15][l4*8]);
            al[i] = *reinterpret_cast<const half8*>(&A1l[o0+i*16+l15][l4*8]);
        }
        #pragma unroll
        for (int j=0;j<4;j++){
            bh[j] = *reinterpret_cast<const half8*>(&Bch[j*16+l15][k0+l4*8]);
            bl[j] = *reinterpret_cast<const half8*>(&Bcl[j*16+l15][k0+l4*8]);
        }
        #pragma unroll
        for (int i=0;i<2;i++)
            #pragma unroll
            for (int j=0;j<4;j++){
                acc[i][j]  = __builtin_amdgcn_mfma_f32_16x16x32_f16(ah[i], bh[j], acc[i][j], 0,0,0);
                acc2[i][j] = __builtin_amdgcn_mfma_f32_16x16x32_f16(ah[i], bl[j], acc2[i][j],0,0,0);
                acc2[i][j] = __builtin_amdgcn_mfma_f32_16x16x32_f16(al[i], bh[j], acc2[i][j],0,0,0);
            }
        __syncthreads();
    }
    // ---- phase 2: irfft, K=256, double-buffered, 1 barrier per chunk ----
    const _Float16* px_h0 = Xh + ((size_t)(b*128)+so2)*256 + sseg*8;
    const _Float16* px_l0 = Xl + ((size_t)(b*128)+so2)*256 + sseg*8;
    const _Float16* px_h1 = px_h0 + 64*256;
    const _Float16* px_l1 = px_l0 + 64*256;
    const _Float16* pt_h  = Tih + (size_t)(n0+so2)*256 + sseg*8;
    const _Float16* pt_l  = Til + (size_t)(n0+so2)*256 + sseg*8;
    half8 rx_h0 = *reinterpret_cast<const half8*>(px_h0);
    half8 rx_l0 = *reinterpret_cast<const half8*>(px_l0);
    half8 rx_h1 = *reinterpret_cast<const half8*>(px_h1);
    half8 rx_l1 = *reinterpret_cast<const half8*>(px_l1);
    half8 rt_h  = *reinterpret_cast<const half8*>(pt_h);
    half8 rt_l  = *reinterpret_cast<const half8*>(pt_l);
    *reinterpret_cast<half8*>(&A2h[0][so2]   [sseg*8]) = rx_h0;
    *reinterpret_cast<half8*>(&A2l[0][so2]   [sseg*8]) = rx_l0;
    *reinterpret_cast<half8*>(&A2h[0][so2+64][sseg*8]) = rx_h1;
    *reinterpret_cast<half8*>(&A2l[0][so2+64][sseg*8]) = rx_l1;
    *reinterpret_cast<half8*>(&B2h[0][so2][sseg*8])    = rt_h;
    *reinterpret_cast<half8*>(&B2l[0][so2][sseg*8])    = rt_l;
    __syncthreads();
    for (int it=0; it<8; ++it){
        int cur = it & 1;
        if (it < 7){
            int k = (it+1)*32;
            rx_h0 = *reinterpret_cast<const half8*>(px_h0 + k);
            rx_l0 = *reinterpret_cast<const half8*>(px_l0 + k);
            rx_h1 = *reinterpret_cast<const half8*>(px_h1 + k);
            rx_l1 = *reinterpret_cast<const half8*>(px_l1 + k);
            rt_h  = *reinterpret_cast<const half8*>(pt_h  + k);
            rt_l  = *reinterpret_cast<const half8*>(pt_l  + k);
        }
        half8 ah[2],al[2],bh[4],bl[4];
        #pragma unroll
        for (int i=0;i<2;i++){
            ah[i] = *reinterpret_cast<const half8*>(&A2h[cur][o0+i*16+l15][l4*8]);
            al[i] = *reinterpret_cast<const half8*>(&A2l[cur][o0+i*16+l15][l4*8]);
        }
        #pragma unroll
        for (int j=0;j<4;j++){
            bh[j] = *reinterpret_cast<const half8*>(&B2h[cur][j*16+l15][l4*8]);
            bl[j] = *reinterpret_cast<const half8*>(&B2l[cur][j*16+l15][l4*8]);
        }
        #pragma unroll
        for (int i=0;i<2;i++)
            #pragma unroll
            for (int j=0;j<4;j++){
                acc[i][j]  = __builtin_amdgcn_mfma_f32_16x16x32_f16(ah[i], bh[j], acc[i][j], 0,0,0);
                acc2[i][j] = __builtin_amdgcn_mfma_f32_16x16x32_f16(ah[i], bl[j], acc2[i][j],0,0,0);
                acc2[i][j] = __builtin_amdgcn_mfma_f32_16x16x32_f16(al[i], bh[j], acc2[i][j],0,0,0);
            }
        if (it < 7){
            int nxt = cur ^ 1;
            *reinterpret_cast<half8*>(&A2h[nxt][so2]   [sseg*8]) = rx_h0;
            *reinterpret_cast<half8*>(&A2l[nxt][so2]   [sseg*8]) = rx_l0;
            *reinterpret_cast<half8*>(&A2h[nxt][so2+64][sseg*8]) = rx_h1;
            *reinterpret_cast<half8*>(&A2l[nxt][so2+64][sseg*8]) = rx_l1;
            *reinterpret_cast<half8*>(&B2h[nxt][so2][sseg*8])    = rt_h;
            *reinterpret_cast<half8*>(&B2l[nxt][so2][sseg*8])    = rt_l;
        }
        __syncthreads();
    }
    // epilogue: bias (+gelu), split, write back in place
    #pragma unroll
    for (int i=0;i<2;i++)
        #pragma unroll
        for (int j=0;j<4;j++)
            #pragma unroll
            for (int r=0;r<4;r++){
                int o = o0 + i*16 + l4*4 + r;
                int n = n0 + j*16 + l15;
                float v = acc[i][j][r] + acc2[i][j][r]*LO_INV + convB[layer*128+o];
                if (applyGelu) v = gelu_f(v);
                _Float16 hi,lo; split_f16(v,hi,lo);
                size_t oi = ((size_t)(b*128+o))*4096 + n;
                hh[oi] = hi; hl[oi] = lo;
            }
}

// ---------------- head (MFMA) ----------------
__global__ __launch_bounds__(256) void k_head(
        const _Float16* __restrict__ hh, const _Float16* __restrict__ hl,
        const _Float16* __restrict__ f1h, const _Float16* __restrict__ f1l,
        const float* __restrict__ fc1b,
        const float* __restrict__ fc2W, const float* __restrict__ fc2b,
        float* __restrict__ out){
    __shared__ _Float16 Bch[64][136], Bcl[64][136];
    __shared__ _Float16 Ash[128][40], Asl[128][40];
    __shared__ float red[16][64];
    int n0 = blockIdx.x*64;
    int b  = blockIdx.y;
    int tid = threadIdx.x, lane = tid & 63, w = tid >> 6;
    int l15 = lane & 15, l4 = lane >> 4;
    int j0 = w*32;
    {
        int c = tid & 127, nh = tid >> 7;
        const _Float16* rh = hh + ((size_t)(b*128+c))*4096 + n0 + nh*32;
        const _Float16* rl = hl + ((size_t)(b*128+c))*4096 + n0 + nh*32;
        #pragma unroll
        for (int j=0;j<4;j++){
            half8 vhv = *reinterpret_cast<const half8*>(rh + j*8);
            half8 vlv = *reinterpret_cast<const half8*>(rl + j*8);
            #pragma unroll
            for (int q=0;q<8;q++){
                int n = nh*32 + j*8 + q;
                Bch[n][c] = vhv[q];
                Bcl[n][c] = vlv[q];
            }
        }
    }
    __syncthreads();
    int so2 = tid >> 2, sseg = tid & 3;
    f32x4 acc[2][4] = {}; f32x4 acc2[2][4] = {};
    for (int k0=0;k0<128;k0+=32){
        #pragma unroll
        for (int p=0;p<2;p++){
            int o = p*64 + so2;
            *reinterpret_cast<half8*>(&Ash[o][sseg*8]) =
                *reinterpret_cast<const half8*>(&f1h[(size_t)o*128 + k0 + sseg*8]);
            *reinterpret_cast<half8*>(&Asl[o][sseg*8]) =
                *reinterpret_cast<const half8*>(&f1l[(size_t)o*128 + k0 + sseg*8]);
        }
        __syncthreads();
        half8 ah[2],al[2],bh[4],bl[4];
        #pragma unroll
        for (int i=0;i<2;i++){
            ah[i] = *reinterpret_cast<const half8*>(&Ash[j0+i*16+l15][l4*8]);
            al[i] = *reinterpret_cast<const half8*>(&Asl[j0+i*16+l15][l4*8]);
        }
        #pragma unroll
        for (int j=0;j<4;j++){
            bh[j] = *reinterpret_cast<const half8*>(&Bch[j*16+l15][k0+l4*8]);
            bl[j] = *reinterpret_cast<const half8*>(&Bcl[j*16+l15][k0+l4*8]);
        }
        #pragma unroll
        for (int i=0;i<2;i++)
            #pragma unroll
            for (int j=0;j<4;j++){
                acc[i][j]  = __builtin_amdgcn_mfma_f32_16x16x32_f16(ah[i], bh[j], acc[i][j], 0,0,0);
                acc2[i][j] = __builtin_amdgcn_mfma_f32_16x16x32_f16(ah[i], bl[j], acc2[i][j],0,0,0);
                acc2[i][j] = __builtin_amdgcn_mfma_f32_16x16x32_f16(al[i], bh[j], acc2[i][j],0,0,0);
            }
        __syncthreads();
    }
    float part[4];
    #pragma unroll
    for (int j=0;j<4;j++) part[j] = 0.f;
    #pragma unroll
    for (int i=0;i<2;i++){
        #pragma unroll
        for (int r=0;r<4;r++){
            int jj = j0 + i*16 + l4*4 + r;
            float b1 = fc1b[jj];
            float w2 = fc2W[jj];
            #pragma unroll
            for (int j=0;j<4;j++){
                float v = acc[i][j][r] + acc2[i][j][r]*LO_INV + b1;
                part[j] = fmaf(w2, gelu_f(v), part[j]);
            }
        }
    }
    #pragma unroll
    for (int j=0;j<4;j++) red[w*4+l4][j*16+l15] = part[j];
    __syncthreads();
    if (tid < 64){
        float s = fc2b[0];
        #pragma unroll
        for (int r=0;r<16;r++) s += red[r][tid];
        out[((size_t)b<<12) + n0 + tid] = s;
    }
}

extern "C" void kernel_launch(void* const* d_in, const int* in_sizes, int n_in,
                              void* d_out, int out_size, void* d_ws, size_t ws_size,
                              hipStream_t stream) {
    const float* x     = (const float*)d_in[0];
    const float* fc0W  = (const float*)d_in[1];
    const float* fc0b  = (const float*)d_in[2];
    const float* gateW = (const float*)d_in[3];
    const float* gateB = (const float*)d_in[4];
    const float* wAre  = (const float*)d_in[5];
    const float* wAim  = (const float*)d_in[6];
    const float* wBre  = (const float*)d_in[7];
    const float* wBim  = (const float*)d_in[8];
    const float* convW = (const float*)d_in[9];
    const float* convB = (const float*)d_in[10];
    const float* fc1W  = (const float*)d_in[11];
    const float* fc1b  = (const float*)d_in[12];
    const float* fc2W  = (const float*)d_in[13];
    const float* fc2b  = (const float*)d_in[14];
    float* out = (float*)d_out;
    char*  wsb = (char*)d_ws;

    float* F    = (float*)(wsb + BY_F);
    float* wsum = (float*)(wsb + BY_wsum);
    float* Wcre = (float*)(wsb + BY_Wcre);
    float* Wcim = (float*)(wsb + BY_Wcim);
    float* wl   = (float*)(wsb + BY_wl);
    float* wr   = (float*)(wsb + BY_wr);
    int*   li   = (int*)(wsb + BY_li);
    float* magp = (float*)(wsb + BY_magp);
    float* gate = (float*)(wsb + BY_gate);
    _Float16* hh  = (_Float16*)(wsb + BY_hh);
    _Float16* hl  = (_Float16*)(wsb + BY_hl);
    _Float16* Tfh = (_Float16*)(wsb + BY_Tfh);
    _Float16* Tfl = (_Float16*)(wsb + BY_Tfl);
    _Float16* Tih = (_Float16*)(wsb + BY_Tih);
    _Float16* Til = (_Float16*)(wsb + BY_Til);
    _Float16* Xh  = (_Float16*)(wsb + BY_Xh);
    _Float16* Xl  = (_Float16*)(wsb + BY_Xl);
    _Float16* cWh = (_Float16*)(wsb + BY_cWh);
    _Float16* cWl = (_Float16*)(wsb + BY_cWl);
    _Float16* f1h = (_Float16*)(wsb + BY_f1h);
    _Float16* f1l = (_Float16*)(wsb + BY_f1l);

    k_tables<<<4096, 256, 0, stream>>>(Tfh, Tfl, Tih, Til);
    k_cft_tables<<<160, 128, 0, stream>>>(Wcre, Wcim, wl, wr, li);
    k_wsum<<<dim3(16384,4), 256, 0, stream>>>(wAre, wAim, wBre, wBim, wsum);
    k_wsplit<<<320, 256, 0, stream>>>(convW, fc1W, cWh, cWl, f1h, f1l);
    k_h0<<<16384, 256, 0, stream>>>(x, fc0W, fc0b, hh, hl);

    for (int layer=0; layer<4; layer++){
        k_cft<<<dim3(64,8), 128, 0, stream>>>(hh, hl, Wcre, Wcim, wl, wr, li, magp);
        k_gate<<<64, 128, 0, stream>>>(magp, gateW, gateB, gate, layer);
        k_fdft<<<512, 256, 0, stream>>>(hh, hl, Tfh, Tfl, F);
        k_modemix<<<dim3(64,16), 256, 0, stream>>>(F, wsum, gate, Xh, Xl, layer);
        k_flayer<<<dim3(64,64), 256, 0, stream>>>(Xh, Xl, Tih, Til, cWh, cWl, convB,
                                                  hh, hl, layer, layer<3 ? 1:0);
    }
    k_head<<<dim3(64,64), 256, 0, stream>>>(hh, hl, f1h, f1l, fc1b, fc2W, fc2b, out);
    (void)in_sizes; (void)n_in; (void)out_size; (void)ws_size;
}

// Round 8
// 1390.162 us; speedup vs baseline: 1.8129x; 1.1682x over previous
//
#include <hip/hip_runtime.h>
#include <math.h>

#define B_SZ 64
#define WID 128
#define NPT 4096
#define MODES 128
#define LSEG 20
#define MCH 8
#define LM 160   // LSEG*MCH

typedef _Float16 half8 __attribute__((ext_vector_type(8)));
typedef float f32x4 __attribute__((ext_vector_type(4)));

#define LO_SCALE 2048.0f
#define LO_INV   (1.0f/2048.0f)

// ---------------- workspace layout (bytes), total ~161.6 MB ----------------
static constexpr size_t BY_F    = 0;                       // fp32 [8192][256]
static constexpr size_t BY_wsum = BY_F + 8388608;          // fp32 [4][4][128][128]
static constexpr size_t BY_Wcre = BY_wsum + 1048576;       // fp32 [160][128]
static constexpr size_t BY_Wcim = BY_Wcre + 81920;
static constexpr size_t BY_wl   = BY_Wcim + 81920;         // fp32 [160] (pad)
static constexpr size_t BY_wr   = BY_wl + 1024;
static constexpr size_t BY_li   = BY_wr + 1024;            // int [160]
static constexpr size_t BY_magp = BY_li + 1024;            // fp32 [64][16][128]
static constexpr size_t BY_gate = BY_magp + 524288;        // fp32 [64][128]
static constexpr size_t BY_hh   = BY_gate + 32768;         // f16 [64][128][4096] split-hi
static constexpr size_t BY_hl   = BY_hh + 67108864;        // f16 split-lo
static constexpr size_t BY_Tfh  = BY_hl + 67108864;        // f16 [256][4096]
static constexpr size_t BY_Tfl  = BY_Tfh + 2097152;
static constexpr size_t BY_Tih  = BY_Tfl + 2097152;        // f16 [4096][256]
static constexpr size_t BY_Til  = BY_Tih + 2097152;
static constexpr size_t BY_Xh   = BY_Til + 2097152;        // f16 [64][128][256]
static constexpr size_t BY_Xl   = BY_Xh + 4194304;
static constexpr size_t BY_cWh  = BY_Xl + 4194304;         // f16 [4][128][128]
static constexpr size_t BY_cWl  = BY_cWh + 131072;
static constexpr size_t BY_f1h  = BY_cWl + 131072;         // f16 [128][128]
static constexpr size_t BY_f1l  = BY_f1h + 32768;
static constexpr size_t BY_end  = BY_f1l + 32768;

__device__ __forceinline__ float gelu_f(float x){
    return 0.5f*x*(1.0f+erff(x*0.70710678118654752f));
}
__device__ __forceinline__ void split_f16(float v, _Float16& hi, _Float16& lo){
    hi = (_Float16)v;
    lo = (_Float16)((v - (float)hi)*LO_SCALE);
}

// ---------------- tables (split f16) ----------------
__global__ void k_tables(_Float16* __restrict__ Tfh, _Float16* __restrict__ Tfl,
                         _Float16* __restrict__ Tih, _Float16* __restrict__ Til){
    int idx = blockIdx.x*256 + threadIdx.x;   // 4096*256
    int n = idx >> 8, k2 = idx & 255;
    int f = k2 >> 1;
    int m = (n*f) & 4095;
    double th = (double)m * (3.14159265358979323846/2048.0);
    double s, c; sincos(th, &s, &c);
    float vf = (k2&1) ? (float)(-s) : (float)c;
    _Float16 h1,l1; split_f16(vf, h1, l1);
    Tfh[(size_t)k2*4096 + n] = h1;
    Tfl[(size_t)k2*4096 + n] = l1;
    float vi;
    if (k2 == 0)      vi = 1.0f;
    else if (k2 == 1) vi = 0.0f;
    else              vi = vf;
    _Float16 h2,l2; split_f16(vi, h2, l2);
    Tih[(size_t)n*256 + k2] = h2;
    Til[(size_t)n*256 + k2] = l2;
}

__global__ void k_cft_tables(float* __restrict__ Wre, float* __restrict__ Wim,
                             float* __restrict__ wl, float* __restrict__ wr,
                             int* __restrict__ li){
    int idx = blockIdx.x*128 + threadIdx.x;   // 160*128
    if (idx >= LM*MODES) return;
    int lm = idx >> 7;  int f = idx & 127;
    int l = lm / MCH, m = lm % MCH;
    const double PI = 3.14159265358979323846;
    double nodes[8], Tm[8];
    #pragma unroll
    for (int j=0;j<8;j++){
        nodes[j] = -cos((2.0*j+1.0)*PI/16.0);
        Tm[j] = cos((double)m * acos(nodes[j]));
    }
    double wp = (double)f * PI * 0.05;
    double cwre=0.0, cwim=0.0;
    #pragma unroll
    for (int j=0;j<8;j++){
        double sj, cj; sincos(nodes[j]*wp, &sj, &cj);
        cwre += Tm[j]*cj;
        cwim -= Tm[j]*sj;
    }
    cwre *= 0.025; cwim *= 0.025;
    int r = (f*l) % 20;
    double sa = 2.0*PI*(double)r/20.0;
    double shre = cos(sa), shim = -sin(sa);
    Wre[lm*128+f] = (float)(shre*cwre - shim*cwim);
    Wim[lm*128+f] = (float)(shre*cwim + shim*cwre);
    if (f == 0){
        double v = (double)l/20.0 + 0.025*(nodes[m]+1.0);
        int rr = (int)ceil(v*4095.0);
        if (rr > 4095) rr = 4095;
        if (rr < 1) rr = 1;
        int le = rr-1;
        double tl = (double)le/4095.0, tr = (double)rr/4095.0;
        double wrv = (v - tl)/(tr - tl);
        li[lm] = le;
        wl[lm] = (float)(1.0 - wrv);
        wr[lm] = (float)wrv;
    }
}

// sum wA/wB over mode axis
__global__ void k_wsum(const float* __restrict__ wAre, const float* __restrict__ wAim,
                       const float* __restrict__ wBre, const float* __restrict__ wBim,
                       float* __restrict__ out){
    int row  = blockIdx.x*4 + (threadIdx.x>>6);
    int lane = threadIdx.x & 63;
    const float* src = (blockIdx.y==0)?wAre:(blockIdx.y==1)?wAim:(blockIdx.y==2)?wBre:wBim;
    float v = src[(size_t)row*128 + lane] + src[(size_t)row*128 + 64 + lane];
    #pragma unroll
    for (int o=32;o>0;o>>=1) v += __shfl_down(v, o);
    if (lane==0) out[(size_t)blockIdx.y*65536 + row] = v;
}

// pre-split conv & fc1 weights
__global__ void k_wsplit(const float* __restrict__ convW, const float* __restrict__ fc1W,
                         _Float16* __restrict__ cWh, _Float16* __restrict__ cWl,
                         _Float16* __restrict__ f1h, _Float16* __restrict__ f1l){
    int idx = blockIdx.x*256 + threadIdx.x;   // 81920
    if (idx < 65536){
        _Float16 hi,lo; split_f16(convW[idx], hi, lo);
        cWh[idx]=hi; cWl[idx]=lo;
    } else {
        int j = idx - 65536;
        _Float16 hi,lo; split_f16(fc1W[j], hi, lo);
        f1h[j]=hi; f1l[j]=lo;
    }
}

// ---------------- lift: write split h ----------------
__global__ void k_h0(const float* __restrict__ x, const float* __restrict__ w0,
                     const float* __restrict__ b0,
                     _Float16* __restrict__ hh, _Float16* __restrict__ hl){
    int idx = blockIdx.x*256 + threadIdx.x;  // 64*128*512
    int n8 = idx & 511;
    int w  = (idx >> 9) & 127;
    int b  = idx >> 16;
    int n0 = n8*8;
    float w00 = w0[w*2], w01 = w0[w*2+1], bb = b0[w];
    const float* xr = &x[((size_t)b<<12) + n0];
    float4 x0 = *reinterpret_cast<const float4*>(xr);
    float4 x1 = *reinterpret_cast<const float4*>(xr+4);
    float xv[8]={x0.x,x0.y,x0.z,x0.w,x1.x,x1.y,x1.z,x1.w};
    half8 vh, vl;
    #pragma unroll
    for (int q=0;q<8;q++){
        float g = (float)(n0+q) * (1.0f/4095.0f);
        float v = xv[q]*w00 + g*w01 + bb;
        _Float16 hi,lo; split_f16(v,hi,lo);
        vh[q]=hi; vl[q]=lo;
    }
    size_t o = ((size_t)(b*128+w))*4096 + n0;
    *reinterpret_cast<half8*>(&hh[o]) = vh;
    *reinterpret_cast<half8*>(&hl[o]) = vl;
}

// ---------------- CFT magnitude (16 groups of 8 channels) ----------------
__global__ void k_cft(const _Float16* __restrict__ hh, const _Float16* __restrict__ hl,
                      const float* __restrict__ Wre, const float* __restrict__ Wim,
                      const float* __restrict__ wl, const float* __restrict__ wr,
                      const int* __restrict__ li, float* __restrict__ magp){
    int b = blockIdx.x, cg = blockIdx.y;
    int f = threadIdx.x;   // 128
    __shared__ float sig[LM];
    __shared__ float swl[LM], swr[LM];
    __shared__ int   sli[LM];
    for (int s=f; s<LM; s+=128){ swl[s]=wl[s]; swr[s]=wr[s]; sli[s]=li[s]; }
    __syncthreads();
    float acc = 0.f;
    for (int cc=0; cc<8; cc++){
        int c = cg*8 + cc;
        const _Float16* rh = hh + ((size_t)(b*128+c))*4096;
        const _Float16* rl = hl + ((size_t)(b*128+c))*4096;
        for (int s=f; s<LM; s+=128){
            int le = sli[s];
            float v0 = (float)rh[le]   + (float)rl[le]*LO_INV;
            float v1 = (float)rh[le+1] + (float)rl[le+1]*LO_INV;
            sig[s] = swl[s]*v0 + swr[s]*v1;
        }
        __syncthreads();
        float re=0.f, im=0.f;
        #pragma unroll 8
        for (int s=0;s<LM;s++){
            float sv = sig[s];
            re = fmaf(sv, Wre[s*128+f], re);
            im = fmaf(sv, Wim[s*128+f], im);
        }
        acc += sqrtf(re*re+im*im);
        __syncthreads();
    }
    magp[(b*16+cg)*128 + f] = acc;
}

__global__ void k_gate(const float* __restrict__ magp, const float* __restrict__ gW,
                       const float* __restrict__ gB, float* __restrict__ gate, int layer){
    int b = blockIdx.x, w = threadIdx.x;
    __shared__ float ms[128];
    float s = 0.f;
    #pragma unroll
    for (int g=0; g<16; g++) s += magp[(b*16+g)*128 + w];
    ms[w] = s * (1.0f/128.0f);
    __syncthreads();
    const float* gwr = gW + ((size_t)layer*128 + w)*128;
    float a = gB[layer*128 + w];
    #pragma unroll 8
    for (int fq=0; fq<128; fq++) a = fmaf(ms[fq], gwr[fq], a);
    gate[b*128+w] = 1.0f/(1.0f+expf(-a));
}

// ---------------- forward DFT: dbuf LDS, 2-deep register prefetch ----------------
__global__ __launch_bounds__(256) void k_fdft(
        const _Float16* __restrict__ hh, const _Float16* __restrict__ hl,
        const _Float16* __restrict__ Tfh, const _Float16* __restrict__ Tfl,
        float* __restrict__ F){
    __shared__ _Float16 Ah[2][64][40], Al[2][64][40], Bh[2][64][40], Bl[2][64][40];
    int id = blockIdx.x;
    int swz = (id & 7)*64 + (id >> 3);        // bijective for 512
    int bx = swz & 3, by = swz >> 2;
    int col0 = bx*64, row0 = by*64;
    int tid = threadIdx.x;
    int lane = tid & 63, w = tid >> 6;
    int wr = (w>>1)*32, wc = (w&1)*32;
    int l15 = lane & 15, l4 = lane >> 4;
    f32x4 acc[2][2] = {}; f32x4 acc2[2][2] = {};
    int srow = tid >> 2, sseg = tid & 3;
    const _Float16* pa_h = hh  + (size_t)(row0+srow)*4096 + sseg*8;
    const _Float16* pa_l = hl  + (size_t)(row0+srow)*4096 + sseg*8;
    const _Float16* pb_h = Tfh + (size_t)(col0+srow)*4096 + sseg*8;
    const _Float16* pb_l = Tfl + (size_t)(col0+srow)*4096 + sseg*8;
    half8 Aah,Aal,Abh,Abl, Bah,Bal,Bbh,Bbl;
#define LOADK(sa,sal,sb,sbl,ck) do{ int kk=(ck)*32; \
    sa  = *reinterpret_cast<const half8*>(pa_h + kk); \
    sal = *reinterpret_cast<const half8*>(pa_l + kk); \
    sb  = *reinterpret_cast<const half8*>(pb_h + kk); \
    sbl = *reinterpret_cast<const half8*>(pb_l + kk); }while(0)
#define WRITEK(sa,sal,sb,sbl,buf) do{ \
    *reinterpret_cast<half8*>(&Ah[buf][srow][sseg*8]) = sa; \
    *reinterpret_cast<half8*>(&Al[buf][srow][sseg*8]) = sal; \
    *reinterpret_cast<half8*>(&Bh[buf][srow][sseg*8]) = sb; \
    *reinterpret_cast<half8*>(&Bl[buf][srow][sseg*8]) = sbl; }while(0)
#define MMF(buf) do{ \
    half8 fah[2], fal[2], fbh[2], fbl[2]; \
    _Pragma("unroll") for (int i=0;i<2;i++){ \
        fah[i] = *reinterpret_cast<const half8*>(&Ah[buf][wr + i*16 + l15][l4*8]); \
        fal[i] = *reinterpret_cast<const half8*>(&Al[buf][wr + i*16 + l15][l4*8]); \
        fbh[i] = *reinterpret_cast<const half8*>(&Bh[buf][wc + i*16 + l15][l4*8]); \
        fbl[i] = *reinterpret_cast<const half8*>(&Bl[buf][wc + i*16 + l15][l4*8]); } \
    _Pragma("unroll") for (int i=0;i<2;i++) \
        _Pragma("unroll") for (int j=0;j<2;j++){ \
            acc[i][j]  = __builtin_amdgcn_mfma_f32_16x16x32_f16(fah[i], fbh[j], acc[i][j], 0,0,0); \
            acc2[i][j] = __builtin_amdgcn_mfma_f32_16x16x32_f16(fah[i], fbl[j], acc2[i][j],0,0,0); \
            acc2[i][j] = __builtin_amdgcn_mfma_f32_16x16x32_f16(fal[i], fbh[j], acc2[i][j],0,0,0); } }while(0)
    LOADK(Aah,Aal,Abh,Abl, 0);
    WRITEK(Aah,Aal,Abh,Abl, 0);
    LOADK(Aah,Aal,Abh,Abl, 1);
    LOADK(Bah,Bal,Bbh,Bbl, 2);
    __syncthreads();
    for (int tt = 0; tt < 64; ++tt){
        int t = tt*2;
        MMF(0);
        WRITEK(Aah,Aal,Abh,Abl, 1);          // chunk t+1
        if (t+3 < 128) LOADK(Aah,Aal,Abh,Abl, t+3);
        __syncthreads();
        MMF(1);
        if (t+2 < 128) WRITEK(Bah,Bal,Bbh,Bbl, 0);  // chunk t+2
        if (t+4 < 128) LOADK(Bah,Bal,Bbh,Bbl, t+4);
        __syncthreads();
    }
#undef LOADK
#undef WRITEK
#undef MMF
    #pragma unroll
    for (int i=0;i<2;i++)
        #pragma unroll
        for (int j=0;j<2;j++)
            #pragma unroll
            for (int r=0;r<4;r++){
                int row = row0 + wr + i*16 + l4*4 + r;
                int col = col0 + wc + j*16 + l15;
                F[(size_t)row*256 + col] = acc[i][j][r] + acc2[i][j][r]*LO_INV;
            }
}

// ---------------- mode mix: X = g*(F.wA) + (1-g)*(F.wB), scaled, split ----------------
__global__ __launch_bounds__(256) void k_modemix(const float* __restrict__ F,
        const float* __restrict__ wsum, const float* __restrict__ gate,
        _Float16* __restrict__ Xh, _Float16* __restrict__ Xl, int layer){
    int b = blockIdx.x, og = blockIdx.y;
    __shared__ float Fs[16][256];
    __shared__ float Wa_re[128][8], Wa_im[128][8], Wb_re[128][8], Wb_im[128][8];
    int tid = threadIdx.x;
    for (int e=tid; e<1024; e+=256){
        int i = e>>3, oo = e&7;
        size_t base = ((size_t)layer*128 + i)*128 + og*8 + oo;
        Wa_re[i][oo] = wsum[0*65536 + base];
        Wa_im[i][oo] = wsum[1*65536 + base];
        Wb_re[i][oo] = wsum[2*65536 + base];
        Wb_im[i][oo] = wsum[3*65536 + base];
    }
    int f = tid & 127, half = tid >> 7;
    float pre[4]={},pim[4]={},qre[4]={},qim[4]={};
    for (int i0=0;i0<128;i0+=16){
        for (int e=tid; e<4096; e+=256){
            int ii = e >> 8, k2 = e & 255;
            Fs[ii][k2] = F[((size_t)(b*128 + i0+ii))*256 + k2];
        }
        __syncthreads();
        #pragma unroll
        for (int ii=0; ii<16; ii++){
            float fre = Fs[ii][2*f], fim = Fs[ii][2*f+1];
            int i = i0+ii;
            #pragma unroll
            for (int q=0;q<4;q++){
                int oo = half*4+q;
                float are=Wa_re[i][oo], aim=Wa_im[i][oo];
                float bre=Wb_re[i][oo], bim=Wb_im[i][oo];
                pre[q] = fmaf(fre, are, fmaf(-fim, aim, pre[q]));
                pim[q] = fmaf(fre, aim, fmaf( fim, are, pim[q]));
                qre[q] = fmaf(fre, bre, fmaf(-fim, bim, qre[q]));
                qim[q] = fmaf(fre, bim, fmaf( fim, bre, qim[q]));
            }
        }
        __syncthreads();
    }
    #pragma unroll
    for (int q=0;q<4;q++){
        int o = og*8 + half*4 + q;
        float g = gate[b*128+o];
        float xre = g*pre[q] + (1.f-g)*qre[q];
        float xim = g*pim[q] + (1.f-g)*qim[q];
        float s = (f==0) ? (1.0f/4096.0f) : (2.0f/4096.0f);
        xre *= s; xim *= s;
        if (f==0) xim = 0.f;
        size_t base = ((size_t)(b*128+o))*256 + 2*f;
        _Float16 h1,l1; split_f16(xre,h1,l1); Xh[base]=h1;   Xl[base]=l1;
        _Float16 h2,l2; split_f16(xim,h2,l2); Xh[base+1]=h2; Xl[base+1]=l2;
    }
}

// ---------------- fused in-place layer: unified 12-chunk pipeline ----------------
// chunks 0..3: conv (A=convW, B=transposed h, XOR-swizzled); 4..11: irfft (A=X, B=Ti).
// double-buffered LDS, 2-deep register prefetch, 2 barriers per chunk-pair.
__global__ __launch_bounds__(256) void k_flayer(
    const _Float16* __restrict__ Xh, const _Float16* __restrict__ Xl,
    const _Float16* __restrict__ Tih, const _Float16* __restrict__ Til,
    const _Float16* __restrict__ cWh, const _Float16* __restrict__ cWl,
    const float* __restrict__ convB,
    _Float16* __restrict__ hh, _Float16* __restrict__ hl,
    int layer, int applyGelu){
    __shared__ _Float16 As_h[2][128][40], As_l[2][128][40];   // 40960 B
    __shared__ _Float16 Bs_h[2][64][40],  Bs_l[2][64][40];    // 20480 B
    int n0 = blockIdx.x*64;
    int b  = blockIdx.y;
    int tid = threadIdx.x, lane = tid & 63, w = tid >> 6;
    int l15 = lane & 15, l4 = lane >> 4;
    int o0 = w*32;
    // staging coordinates
    int aro = tid >> 2, asl = tid & 3;          // A rows aro, aro+64; k-slot asl
    int ctc = tid >> 3, ctn = tid & 7;          // conv-B: local c, n-octet
    int ocp = ((tid >> 6) ^ (tid & 3));         // conv-B write octet (swizzled)
    // global base pointers (element units)
    const _Float16* cA_h = cWh + (size_t)layer*16384 + (size_t)aro*128 + asl*8;
    const _Float16* cA_l = cWl + (size_t)layer*16384 + (size_t)aro*128 + asl*8;
    const _Float16* xA_h = Xh + ((size_t)(b*128 + aro))*256 + asl*8;
    const _Float16* xA_l = Xl + ((size_t)(b*128 + aro))*256 + asl*8;
    const _Float16* hB_h = hh + ((size_t)(b*128 + ctc))*4096 + n0 + ctn*8;
    const _Float16* hB_l = hl + ((size_t)(b*128 + ctc))*4096 + n0 + ctn*8;
    const _Float16* tB_h = Tih + (size_t)(n0 + aro)*256 + asl*8;
    const _Float16* tB_l = Til + (size_t)(n0 + aro)*256 + asl*8;
    f32x4 acc[2][4] = {}; f32x4 acc2[2][4] = {};
    half8 rA[6], rB[6];   // [a0h,a0l,a1h,a1l,bh,bl]
#define LOADR(r,ck) do{ \
    if ((ck) < 4){ int kk = (ck)*32; \
        r[0] = *reinterpret_cast<const half8*>(cA_h + kk); \
        r[1] = *reinterpret_cast<const half8*>(cA_l + kk); \
        r[2] = *reinterpret_cast<const half8*>(cA_h + 64*128 + kk); \
        r[3] = *reinterpret_cast<const half8*>(cA_l + 64*128 + kk); \
        r[4] = *reinterpret_cast<const half8*>(hB_h + (size_t)(ck)*32*4096); \
        r[5] = *reinterpret_cast<const half8*>(hB_l + (size_t)(ck)*32*4096); \
    } else { int kk = ((ck)-4)*32; \
        r[0] = *reinterpret_cast<const half8*>(xA_h + kk); \
        r[1] = *reinterpret_cast<const half8*>(xA_l + kk); \
        r[2] = *reinterpret_cast<const half8*>(xA_h + 64*256 + kk); \
        r[3] = *reinterpret_cast<const half8*>(xA_l + 64*256 + kk); \
        r[4] = *reinterpret_cast<const half8*>(tB_h + kk); \
        r[5] = *reinterpret_cast<const half8*>(tB_l + kk); } }while(0)
#define WRITER(r,buf,ck) do{ \
    *reinterpret_cast<half8*>(&As_h[buf][aro][asl*8])    = r[0]; \
    *reinterpret_cast<half8*>(&As_l[buf][aro][asl*8])    = r[1]; \
    *reinterpret_cast<half8*>(&As_h[buf][aro+64][asl*8]) = r[2]; \
    *reinterpret_cast<half8*>(&As_l[buf][aro+64][asl*8]) = r[3]; \
    if ((ck) < 4){ \
        _Pragma("unroll") for (int j2=0;j2<8;j2++){ \
            int n = ctn*8 + j2; \
            Bs_h[buf][n][ocp*8 + (ctc&7)] = r[4][j2]; \
            Bs_l[buf][n][ocp*8 + (ctc&7)] = r[5][j2]; } \
    } else { \
        *reinterpret_cast<half8*>(&Bs_h[buf][aro][asl*8]) = r[4]; \
        *reinterpret_cast<half8*>(&Bs_l[buf][aro][asl*8]) = r[5]; } }while(0)
#define MML(buf,ck) do{ \
    half8 ah[2], al[2], bh[4], bl[4]; \
    _Pragma("unroll") for (int i=0;i<2;i++){ \
        ah[i] = *reinterpret_cast<const half8*>(&As_h[buf][o0+i*16+l15][l4*8]); \
        al[i] = *reinterpret_cast<const half8*>(&As_l[buf][o0+i*16+l15][l4*8]); } \
    if ((ck) < 4){ \
        _Pragma("unroll") for (int j=0;j<4;j++){ \
            int n = j*16 + l15; int sl = (l4 ^ ((n>>3)&3)); \
            bh[j] = *reinterpret_cast<const half8*>(&Bs_h[buf][n][sl*8]); \
            bl[j] = *reinterpret_cast<const half8*>(&Bs_l[buf][n][sl*8]); } \
    } else { \
        _Pragma("unroll") for (int j=0;j<4;j++){ \
            bh[j] = *reinterpret_cast<const half8*>(&Bs_h[buf][j*16+l15][l4*8]); \
            bl[j] = *reinterpret_cast<const half8*>(&Bs_l[buf][j*16+l15][l4*8]); } } \
    _Pragma("unroll") for (int i=0;i<2;i++) \
        _Pragma("unroll") for (int j=0;j<4;j++){ \
            acc[i][j]  = __builtin_amdgcn_mfma_f32_16x16x32_f16(ah[i], bh[j], acc[i][j], 0,0,0); \
            acc2[i][j] = __builtin_amdgcn_mfma_f32_16x16x32_f16(ah[i], bl[j], acc2[i][j],0,0,0); \
            acc2[i][j] = __builtin_amdgcn_mfma_f32_16x16x32_f16(al[i], bh[j], acc2[i][j],0,0,0); } }while(0)
    LOADR(rA, 0);
    WRITER(rA, 0, 0);
    LOADR(rA, 1);
    LOADR(rB, 2);
    __syncthreads();
    #pragma unroll
    for (int tt=0; tt<6; ++tt){
        const int t = 2*tt;
        MML(0, t);
        WRITER(rA, 1, t+1);
        if (t+3 < 12) LOADR(rA, t+3);
        __syncthreads();
        MML(1, t+1);
        if (t+2 < 12) WRITER(rB, 0, t+2);
        if (t+4 < 12) LOADR(rB, t+4);
        __syncthreads();
    }
#undef LOADR
#undef WRITER
#undef MML
    // epilogue: bias (+gelu), split, write back in place
    #pragma unroll
    for (int i=0;i<2;i++)
        #pragma unroll
        for (int j=0;j<4;j++)
            #pragma unroll
            for (int r=0;r<4;r++){
                int o = o0 + i*16 + l4*4 + r;
                int n = n0 + j*16 + l15;
                float v = acc[i][j][r] + acc2[i][j][r]*LO_INV + convB[layer*128+o];
                if (applyGelu) v = gelu_f(v);
                _Float16 hi,lo; split_f16(v,hi,lo);
                size_t oi = ((size_t)(b*128+o))*4096 + n;
                hh[oi] = hi; hl[oi] = lo;
            }
}

// ---------------- head (MFMA) ----------------
__global__ __launch_bounds__(256) void k_head(
        const _Float16* __restrict__ hh, const _Float16* __restrict__ hl,
        const _Float16* __restrict__ f1h, const _Float16* __restrict__ f1l,
        const float* __restrict__ fc1b,
        const float* __restrict__ fc2W, const float* __restrict__ fc2b,
        float* __restrict__ out){
    __shared__ _Float16 Bch[64][136], Bcl[64][136];
    __shared__ _Float16 Ash[128][40], Asl[128][40];
    __shared__ float red[16][64];
    int n0 = blockIdx.x*64;
    int b  = blockIdx.y;
    int tid = threadIdx.x, lane = tid & 63, w = tid >> 6;
    int l15 = lane & 15, l4 = lane >> 4;
    int j0 = w*32;
    {
        int c = tid & 127, nh = tid >> 7;
        const _Float16* rh = hh + ((size_t)(b*128+c))*4096 + n0 + nh*32;
        const _Float16* rl = hl + ((size_t)(b*128+c))*4096 + n0 + nh*32;
        #pragma unroll
        for (int j=0;j<4;j++){
            half8 vhv = *reinterpret_cast<const half8*>(rh + j*8);
            half8 vlv = *reinterpret_cast<const half8*>(rl + j*8);
            #pragma unroll
            for (int q=0;q<8;q++){
                int n = nh*32 + j*8 + q;
                Bch[n][c] = vhv[q];
                Bcl[n][c] = vlv[q];
            }
        }
    }
    __syncthreads();
    int so2 = tid >> 2, sseg = tid & 3;
    f32x4 acc[2][4] = {}; f32x4 acc2[2][4] = {};
    for (int k0=0;k0<128;k0+=32){
        #pragma unroll
        for (int p=0;p<2;p++){
            int o = p*64 + so2;
            *reinterpret_cast<half8*>(&Ash[o][sseg*8]) =
                *reinterpret_cast<const half8*>(&f1h[(size_t)o*128 + k0 + sseg*8]);
            *reinterpret_cast<half8*>(&Asl[o][sseg*8]) =
                *reinterpret_cast<const half8*>(&f1l[(size_t)o*128 + k0 + sseg*8]);
        }
        __syncthreads();
        half8 ah[2],al[2],bh[4],bl[4];
        #pragma unroll
        for (int i=0;i<2;i++){
            ah[i] = *reinterpret_cast<const half8*>(&Ash[j0+i*16+l15][l4*8]);
            al[i] = *reinterpret_cast<const half8*>(&Asl[j0+i*16+l15][l4*8]);
        }
        #pragma unroll
        for (int j=0;j<4;j++){
            bh[j] = *reinterpret_cast<const half8*>(&Bch[j*16+l15][k0+l4*8]);
            bl[j] = *reinterpret_cast<const half8*>(&Bcl[j*16+l15][k0+l4*8]);
        }
        #pragma unroll
        for (int i=0;i<2;i++)
            #pragma unroll
            for (int j=0;j<4;j++){
                acc[i][j]  = __builtin_amdgcn_mfma_f32_16x16x32_f16(ah[i], bh[j], acc[i][j], 0,0,0);
                acc2[i][j] = __builtin_amdgcn_mfma_f32_16x16x32_f16(ah[i], bl[j], acc2[i][j],0,0,0);
                acc2[i][j] = __builtin_amdgcn_mfma_f32_16x16x32_f16(al[i], bh[j], acc2[i][j],0,0,0);
            }
        __syncthreads();
    }
    float part[4];
    #pragma unroll
    for (int j=0;j<4;j++) part[j] = 0.f;
    #pragma unroll
    for (int i=0;i<2;i++){
        #pragma unroll
        for (int r=0;r<4;r++){
            int jj = j0 + i*16 + l4*4 + r;
            float b1 = fc1b[jj];
            float w2 = fc2W[jj];
            #pragma unroll
            for (int j=0;j<4;j++){
                float v = acc[i][j][r] + acc2[i][j][r]*LO_INV + b1;
                part[j] = fmaf(w2, gelu_f(v), part[j]);
            }
        }
    }
    #pragma unroll
    for (int j=0;j<4;j++) red[w*4+l4][j*16+l15] = part[j];
    __syncthreads();
    if (tid < 64){
        float s = fc2b[0];
        #pragma unroll
        for (int r=0;r<16;r++) s += red[r][tid];
        out[((size_t)b<<12) + n0 + tid] = s;
    }
}

extern "C" void kernel_launch(void* const* d_in, const int* in_sizes, int n_in,
                              void* d_out, int out_size, void* d_ws, size_t ws_size,
                              hipStream_t stream) {
    const float* x     = (const float*)d_in[0];
    const float* fc0W  = (const float*)d_in[1];
    const float* fc0b  = (const float*)d_in[2];
    const float* gateW = (const float*)d_in[3];
    const float* gateB = (const float*)d_in[4];
    const float* wAre  = (const float*)d_in[5];
    const float* wAim  = (const float*)d_in[6];
    const float* wBre  = (const float*)d_in[7];
    const float* wBim  = (const float*)d_in[8];
    const float* convW = (const float*)d_in[9];
    const float* convB = (const float*)d_in[10];
    const float* fc1W  = (const float*)d_in[11];
    const float* fc1b  = (const float*)d_in[12];
    const float* fc2W  = (const float*)d_in[13];
    const float* fc2b  = (const float*)d_in[14];
    float* out = (float*)d_out;
    char*  wsb = (char*)d_ws;

    float* F    = (float*)(wsb + BY_F);
    float* wsum = (float*)(wsb + BY_wsum);
    float* Wcre = (float*)(wsb + BY_Wcre);
    float* Wcim = (float*)(wsb + BY_Wcim);
    float* wl   = (float*)(wsb + BY_wl);
    float* wr   = (float*)(wsb + BY_wr);
    int*   li   = (int*)(wsb + BY_li);
    float* magp = (float*)(wsb + BY_magp);
    float* gate = (float*)(wsb + BY_gate);
    _Float16* hh  = (_Float16*)(wsb + BY_hh);
    _Float16* hl  = (_Float16*)(wsb + BY_hl);
    _Float16* Tfh = (_Float16*)(wsb + BY_Tfh);
    _Float16* Tfl = (_Float16*)(wsb + BY_Tfl);
    _Float16* Tih = (_Float16*)(wsb + BY_Tih);
    _Float16* Til = (_Float16*)(wsb + BY_Til);
    _Float16* Xh  = (_Float16*)(wsb + BY_Xh);
    _Float16* Xl  = (_Float16*)(wsb + BY_Xl);
    _Float16* cWh = (_Float16*)(wsb + BY_cWh);
    _Float16* cWl = (_Float16*)(wsb + BY_cWl);
    _Float16* f1h = (_Float16*)(wsb + BY_f1h);
    _Float16* f1l = (_Float16*)(wsb + BY_f1l);

    k_tables<<<4096, 256, 0, stream>>>(Tfh, Tfl, Tih, Til);
    k_cft_tables<<<160, 128, 0, stream>>>(Wcre, Wcim, wl, wr, li);
    k_wsum<<<dim3(16384,4), 256, 0, stream>>>(wAre, wAim, wBre, wBim, wsum);
    k_wsplit<<<320, 256, 0, stream>>>(convW, fc1W, cWh, cWl, f1h, f1l);
    k_h0<<<16384, 256, 0, stream>>>(x, fc0W, fc0b, hh, hl);

    for (int layer=0; layer<4; layer++){
        k_cft<<<dim3(64,16), 128, 0, stream>>>(hh, hl, Wcre, Wcim, wl, wr, li, magp);
        k_gate<<<64, 128, 0, stream>>>(magp, gateW, gateB, gate, layer);
        k_fdft<<<512, 256, 0, stream>>>(hh, hl, Tfh, Tfl, F);
        k_modemix<<<dim3(64,16), 256, 0, stream>>>(F, wsum, gate, Xh, Xl, layer);
        k_flayer<<<dim3(64,64), 256, 0, stream>>>(Xh, Xl, Tih, Til, cWh, cWl, convB,
                                                  hh, hl, layer, layer<3 ? 1:0);
    }
    k_head<<<dim3(64,64), 256, 0, stream>>>(hh, hl, f1h, f1l, fc1b, fc2W, fc2b, out);
    (void)in_sizes; (void)n_in; (void)out_size; (void)ws_size;
}